// Round 8
// baseline (2370.659 us; speedup 1.0000x reference)
//
#include <hip/hip_runtime.h>
#include <hip/hip_bf16.h>
#include <math.h>

#define D_MODEL 384
#define D_INNER 768
#define D_STATE 16
#define DT_RANK 24
#define NXP 56          // DT_RANK + 2*D_STATE
#define LTOK 196
#define BSZ 16
#define NROW 3136       // BSZ * LTOK
#define NDEPTH 24
#define NCLS 1000

constexpr float kSqrtC   = 0.70710678118654752440f;
constexpr float kMaxNorm = 0.95f / 0.70710678118654752440f;   // 1.3435029...

typedef unsigned short u16;
typedef short  bf16x8 __attribute__((ext_vector_type(8)));
typedef u16    u16x8  __attribute__((ext_vector_type(8)));
typedef float  f32x4  __attribute__((ext_vector_type(4)));

__device__ __forceinline__ float clampf(float x, float lo, float hi) {
  return fminf(fmaxf(x, lo), hi);
}

// f32 -> bf16 (RNE)
__device__ __forceinline__ u16 f2bf(float f) {
  union { float f; unsigned u; } v; v.f = f;
  return (u16)((v.u + 0x7FFFu + ((v.u >> 16) & 1u)) >> 16);
}
// bf16 -> f32
__device__ __forceinline__ float bf2f(u16 s) {
  union { unsigned u; float f; } v; v.u = ((unsigned)s) << 16;
  return v.f;
}

// async global->LDS, 16 B per lane. LDS dest = wave-uniform base + lane*16.
__device__ __forceinline__ void gload16(const u16* g, u16* l) {
  __builtin_amdgcn_global_load_lds(
      (const __attribute__((address_space(1))) unsigned int*)g,
      (__attribute__((address_space(3))) unsigned int*)l, 16, 0, 0);
}

// ---- fast transcendentals (1e-7-ish rel err; invisible under bf16) --------
__device__ __forceinline__ float fsig(float x) {
  return __fdividef(1.f, 1.f + __expf(-x));
}
__device__ __forceinline__ float fsilu(float x) { return x * fsig(x); }
__device__ __forceinline__ float fsoftplus(float x) {
  return (x > 20.f) ? x : __logf(1.f + __expf(x));
}
__device__ __forceinline__ float ftanh(float x) {
  float e = __expf(2.f * x);
  return __fdividef(e - 1.f, e + 1.f);
}
__device__ __forceinline__ float fatanh(float x) {   // x in [0, 0.95]
  return 0.5f * __logf(__fdividef(1.f + x, 1.f - x));
}

// 64-lane wave reduction (no LDS, no barriers)
__device__ __forceinline__ float waveSum(float v) {
#pragma unroll
  for (int o = 1; o < 64; o <<= 1) v += __shfl_xor(v, o, 64);
  return v;
}

// block=128 sum-reduce with broadcast (stem kernels only).
__device__ __forceinline__ float blockSum128(float v, float* sm) {
#pragma unroll
  for (int o = 32; o > 0; o >>= 1) v += __shfl_down(v, o, 64);
  __syncthreads();
  if ((threadIdx.x & 63) == 0) sm[threadIdx.x >> 6] = v;
  __syncthreads();
  return sm[0] + sm[1];
}

// ----------------- f32 -> bf16 bulk convert, 5 tensors in one launch --------
__global__ __launch_bounds__(256) void k_cvt5(
    const float* __restrict__ s0, u16* __restrict__ d0, int n0,
    const float* __restrict__ s1, u16* __restrict__ d1, int n1,
    const float* __restrict__ s2, u16* __restrict__ d2, int n2,
    const float* __restrict__ s3, u16* __restrict__ d3, int n3,
    const float* __restrict__ s4, u16* __restrict__ d4, int n4) {
  int i = blockIdx.x * 256 + threadIdx.x;
  const float* s; u16* d;
  if (i < n0) { s = s0; d = d0; }
  else if ((i -= n0) < n1) { s = s1; d = d1; }
  else if ((i -= n1) < n2) { s = s2; d = d2; }
  else if ((i -= n2) < n3) { s = s3; d = d3; }
  else if ((i -= n3) < n4) { s = s4; d = d4; }
  else return;
  float4 v = ((const float4*)s)[i];
  short4 o = {(short)f2bf(v.x), (short)f2bf(v.y), (short)f2bf(v.z),
              (short)f2bf(v.w)};
  *(short4*)&d[(size_t)i * 4] = o;
}

// ------------------------------------------------- im2col (emit bf16) ------
__global__ __launch_bounds__(256) void k_im2col(const float* __restrict__ x,
                                                u16* __restrict__ P) {
  size_t idx = (size_t)blockIdx.x * 256 + threadIdx.x;
  if (idx >= (size_t)NROW * 768) return;
  int k = (int)(idx % 768);
  int r = (int)(idx / 768);
  int b = r / LTOK, t = r % LTOK;
  int hp = t / 14, wp = t % 14;
  int c = k / 256, rem = k % 256, i = rem / 16, j = rem % 16;
  P[idx] = f2bf(
      x[(((size_t)(b * 3 + c) * 224) + hp * 16 + i) * 224 + wp * 16 + j]);
}

// ------------------------- pure-bf16 MFMA GEMM 64x64: C = A*W^T (+b, act) ---
// A (M,K) bf16 rm stride lda. W (Nv,K) bf16 rm tight. REQUIRES K % 64 == 0.
// Double-buffered LDS, ONE barrier per K-step: stage(k+1) issued before
// compute(k), so global_load_lds overlaps ds_read+MFMA. XOR swizzle on both
// global source and ds_read. Rows >= Nv read garbage; their output columns
// are discarded.
__global__ __launch_bounds__(256) void k_gemm_bb(
    const u16* __restrict__ A, const u16* __restrict__ W,
    const float* __restrict__ bias, void* __restrict__ Cn,
    void* __restrict__ Ct, int K, int lda, int ldc, int ldct, int Nv, int act,
    int obf, int obf_t) {
  __shared__ u16 As[2][64 * 64];
  __shared__ u16 Ws[2][64 * 64];
  const int tid = threadIdx.x;
  const int m0 = blockIdx.x * 64;
  const int n0 = blockIdx.y * 64;
  const int lane = tid & 63;
  const int w = tid >> 6;
  const int wm = w & 1, wn = w >> 1;
  const int lm = lane & 15;
  const int quad = lane >> 4;
  const int r8 = lane >> 3;          // row within chunk, 0..7
  const int t8 = lane & 7;           // 16B slot within row
  const int gsg = t8 ^ r8;           // pre-swizzled global k-segment
  const int s = lm & 7;              // read-time swizzle

  f32x4 acc[2][2];
#pragma unroll
  for (int i = 0; i < 2; i++)
#pragma unroll
    for (int j = 0; j < 2; j++) acc[i][j] = (f32x4){0.f, 0.f, 0.f, 0.f};

  auto stage = [&](int buf, int k0) {
#pragma unroll
    for (int cc = 0; cc < 2; cc++) {
      const int c = 2 * w + cc;            // chunk 0..7 (wave-uniform)
      const int row = c * 8 + r8;
      gload16(A + (size_t)(m0 + row) * lda + k0 + gsg * 8, &As[buf][c * 512]);
      gload16(W + (size_t)(n0 + row) * K + k0 + gsg * 8, &Ws[buf][c * 512]);
    }
  };
  stage(0, 0);
  __syncthreads();
  int cur = 0;
  for (int k0 = 0; k0 < K; k0 += 64) {
    if (k0 + 64 < K) stage(cur ^ 1, k0 + 64);
#pragma unroll
    for (int h = 0; h < 2; h++) {
      const int col = (((h << 2) + quad) ^ s) << 3;
      bf16x8 af[2], bfr[2];
#pragma unroll
      for (int i = 0; i < 2; i++) {
        af[i]  = *(bf16x8*)&As[cur][(wm * 32 + i * 16 + lm) * 64 + col];
        bfr[i] = *(bf16x8*)&Ws[cur][(wn * 32 + i * 16 + lm) * 64 + col];
      }
#pragma unroll
      for (int i = 0; i < 2; i++)
#pragma unroll
        for (int j = 0; j < 2; j++)
          acc[i][j] = __builtin_amdgcn_mfma_f32_16x16x32_bf16(
              af[i], bfr[j], acc[i][j], 0, 0, 0);
    }
    __syncthreads();  // drains prefetch (vmcnt) + guards LDS reuse
    cur ^= 1;
  }
  // epilogue: C/D layout col=lane&15, row=quad*4+reg
#pragma unroll
  for (int i = 0; i < 2; i++) {
#pragma unroll
    for (int j = 0; j < 2; j++) {
      int cg = n0 + wn * 32 + j * 16 + lm;
      if (cg >= Nv) continue;
      float bj = bias ? bias[cg] : 0.f;
      float o[4];
      int rgb = m0 + wm * 32 + i * 16 + quad * 4;
#pragma unroll
      for (int reg = 0; reg < 4; reg++) {
        float v = acc[i][j][reg] + bj;
        if (act == 1) v = fsoftplus(v);
        else if (act == 2 && cg >= 768) v = fsilu(v);
        o[reg] = v;
      }
      if (Cn) {
#pragma unroll
        for (int reg = 0; reg < 4; reg++) {
          if (obf) ((u16*)Cn)[(size_t)(rgb + reg) * ldc + cg] = f2bf(o[reg]);
          else ((float*)Cn)[(size_t)(rgb + reg) * ldc + cg] = o[reg];
        }
      }
      if (Ct) {
        if (obf_t) {
          short4 o4 = {(short)f2bf(o[0]), (short)f2bf(o[1]), (short)f2bf(o[2]),
                       (short)f2bf(o[3])};
          *(short4*)&((u16*)Ct)[(size_t)cg * ldct + rgb] = o4;
        } else {
          float4 o4 = {o[0], o[1], o[2], o[3]};
          *(float4*)&((float*)Ct)[(size_t)cg * ldct + rgb] = o4;
        }
      }
    }
  }
}

// ----------- in_proj GEMM 64x128: x-half -> Cx rm [r][768], z-half ->
// silu'd TRANSPOSED Zt [768][NROW] (coalesced gate reads in pscan).
// K%64==0. Same double-buffered single-barrier pipeline.
__global__ __launch_bounds__(256) void k_gemm_n128(
    const u16* __restrict__ A, const u16* __restrict__ W,
    u16* __restrict__ Cx, u16* __restrict__ Zt, int K, int lda, int ldc) {
  __shared__ u16 As[2][64 * 64];
  __shared__ u16 Ws[2][128 * 64];
  const int tid = threadIdx.x;
  const int m0 = blockIdx.x * 64;
  const int n0 = blockIdx.y * 128;
  const int lane = tid & 63;
  const int w = tid >> 6;
  const int lm = lane & 15;
  const int quad = lane >> 4;
  const int r8 = lane >> 3;
  const int t8 = lane & 7;
  const int gsg = t8 ^ r8;
  const int s = lm & 7;

  f32x4 acc[4][2];
#pragma unroll
  for (int i = 0; i < 4; i++)
#pragma unroll
    for (int j = 0; j < 2; j++) acc[i][j] = (f32x4){0.f, 0.f, 0.f, 0.f};

  auto stage = [&](int buf, int k0) {
#pragma unroll
    for (int cc = 0; cc < 2; cc++) {
      const int c = 2 * w + cc;            // A chunks 0..7
      gload16(A + (size_t)(m0 + c * 8 + r8) * lda + k0 + gsg * 8,
              &As[buf][c * 512]);
    }
#pragma unroll
    for (int cc = 0; cc < 4; cc++) {
      const int c = 4 * w + cc;            // W chunks 0..15
      gload16(W + (size_t)(n0 + c * 8 + r8) * K + k0 + gsg * 8,
              &Ws[buf][c * 512]);
    }
  };
  stage(0, 0);
  __syncthreads();
  int cur = 0;
  for (int k0 = 0; k0 < K; k0 += 64) {
    if (k0 + 64 < K) stage(cur ^ 1, k0 + 64);
#pragma unroll
    for (int h = 0; h < 2; h++) {
      const int col = (((h << 2) + quad) ^ s) << 3;
      bf16x8 af[4], bfr[2];
#pragma unroll
      for (int i = 0; i < 4; i++)
        af[i] = *(bf16x8*)&As[cur][(i * 16 + lm) * 64 + col];
#pragma unroll
      for (int j = 0; j < 2; j++)
        bfr[j] = *(bf16x8*)&Ws[cur][(w * 32 + j * 16 + lm) * 64 + col];
#pragma unroll
      for (int i = 0; i < 4; i++)
#pragma unroll
        for (int j = 0; j < 2; j++)
          acc[i][j] = __builtin_amdgcn_mfma_f32_16x16x32_bf16(
              af[i], bfr[j], acc[i][j], 0, 0, 0);
    }
    __syncthreads();
    cur ^= 1;
  }
  // n0 is 0..767 (x-half) or 768..1535 (z-half) — never mixed (128 | 768).
#pragma unroll
  for (int i = 0; i < 4; i++) {
#pragma unroll
    for (int j = 0; j < 2; j++) {
      int cg = n0 + w * 32 + j * 16 + lm;
      int rgb = m0 + i * 16 + quad * 4;
      if (cg < 768) {
#pragma unroll
        for (int reg = 0; reg < 4; reg++)
          Cx[(size_t)(rgb + reg) * ldc + cg] = f2bf(acc[i][j][reg]);
      } else {
        short4 o4 = {(short)f2bf(fsilu(acc[i][j][0])),
                     (short)f2bf(fsilu(acc[i][j][1])),
                     (short)f2bf(fsilu(acc[i][j][2])),
                     (short)f2bf(fsilu(acc[i][j][3]))};
        *(short4*)&Zt[(size_t)(cg - 768) * NROW + rgb] = o4;
      }
    }
  }
}

// ------------------ stem a: expmap0(tokens) -> bf16 h + ||h|| ---------------
__global__ __launch_bounds__(128) void k_stem_a(const float* __restrict__ tok,
                                                u16* __restrict__ hb,
                                                float* __restrict__ xn) {
  __shared__ float sm[2];
  const int r = blockIdx.x, tid = threadIdx.x;
  float v[3];
#pragma unroll
  for (int j = 0; j < 3; j++) v[j] = tok[(size_t)r * D_MODEL + tid + j * 128];
  float s = blockSum128(v[0] * v[0] + v[1] * v[1] + v[2] * v[2], sm);
  float n = sqrtf(s + 1e-15f);
  float nc = clampf(n, 1e-8f, 5.f);
  float ke = tanhf(kSqrtC * nc) / (kSqrtC * nc);
  float rn = sqrtf(ke * ke * s + 1e-15f);
  float sc = rn > kMaxNorm ? kMaxNorm / rn : 1.f;
  float kk = ke * sc;
#pragma unroll
  for (int j = 0; j < 3; j++)
    hb[(size_t)r * D_MODEL + tid + j * 128] = f2bf(kk * v[j]);
  if (tid == 0) xn[r] = fmaxf(sqrtf(kk * kk * s + 1e-15f), 1e-8f);
}

// --- stem b: mobius_matvec tail + mobius_add(hyp_b) + hyp_LN + pos + expmap -
__global__ __launch_bounds__(128) void k_stem_b(
    const float* __restrict__ mx, const float* __restrict__ xn,
    const float* __restrict__ hyp_b, const float* __restrict__ pe_g,
    const float* __restrict__ pe_b, const float* __restrict__ pos,
    float* __restrict__ outh) {
  __shared__ float sm[2];
  const int r = blockIdx.x, tid = threadIdx.x;
  const int t = r % LTOK;
  float mv[3], bv[3];
  int dd[3];
#pragma unroll
  for (int j = 0; j < 3; j++) {
    dd[j] = tid + j * 128;
    mv[j] = mx[(size_t)r * D_MODEL + dd[j]];
    bv[j] = hyp_b[dd[j]];
  }
  float smx = blockSum128(mv[0] * mv[0] + mv[1] * mv[1] + mv[2] * mv[2], sm);
  float mxn = fmaxf(sqrtf(smx + 1e-15f), 1e-8f);
  float xnv = xn[r];
  float tt = tanhf(mxn / xnv * atanhf(fminf(kSqrtC * xnv, 1.f - 1e-5f)));
  float kres = tt / (mxn * kSqrtC);
  float res[3];
#pragma unroll
  for (int j = 0; j < 3; j++) res[j] = kres * mv[j];
  float xy = blockSum128(res[0] * bv[0] + res[1] * bv[1] + res[2] * bv[2], sm);
  float y2 = blockSum128(bv[0] * bv[0] + bv[1] * bv[1] + bv[2] * bv[2], sm);
  float x2 = kres * kres * smx;
  float al = 1.f + xy + 0.5f * y2;
  float be = 1.f - 0.5f * x2;
  float den = fmaxf(1.f + xy + 0.25f * x2 * y2, 1e-15f);
  float h1[3];
#pragma unroll
  for (int j = 0; j < 3; j++) h1[j] = (al * res[j] + be * bv[j]) / den;
  float s1 = blockSum128(h1[0] * h1[0] + h1[1] * h1[1] + h1[2] * h1[2], sm);
  float n1 = sqrtf(s1 + 1e-15f);
  float nc1 = clampf(n1, 1e-8f, kMaxNorm);
  float kl = atanhf(fminf(kSqrtC * nc1, 0.95f)) / (kSqrtC * nc1);
  float tl[3];
#pragma unroll
  for (int j = 0; j < 3; j++) tl[j] = kl * h1[j];
  float mean = blockSum128(tl[0] + tl[1] + tl[2], sm) * (1.f / 384.f);
  float dv = 0.f;
#pragma unroll
  for (int j = 0; j < 3; j++) { float d = tl[j] - mean; dv += d * d; }
  float var = blockSum128(dv, sm) * (1.f / 383.f);
  float inv = 1.f / (sqrtf(var) + 1e-5f);
  float g[3];
#pragma unroll
  for (int j = 0; j < 3; j++)
    g[j] = (tl[j] - mean) * inv * pe_g[dd[j]] + pe_b[dd[j]];
  float sg = blockSum128(g[0] * g[0] + g[1] * g[1] + g[2] * g[2], sm);
  float ng = sqrtf(sg + 1e-15f);
  float nc2 = clampf(ng, 1e-8f, 5.f);
  float ke = tanhf(kSqrtC * nc2) / (kSqrtC * nc2);
  float rn = sqrtf(ke * ke * sg + 1e-15f);
  float sc = rn > kMaxNorm ? kMaxNorm / rn : 1.f;
  float kk = ke * sc;
  float s2 = kk * kk * sg;
  float n3 = sqrtf(s2 + 1e-15f);
  float nc3 = clampf(n3, 1e-8f, kMaxNorm);
  float kl2 = atanhf(fminf(kSqrtC * nc3, 0.95f)) / (kSqrtC * nc3);
  float v[3];
#pragma unroll
  for (int j = 0; j < 3; j++)
    v[j] = kl2 * kk * g[j] + pos[(size_t)t * D_MODEL + dd[j]];
  float sv = blockSum128(v[0] * v[0] + v[1] * v[1] + v[2] * v[2], sm);
  float nv = sqrtf(sv + 1e-15f);
  float nc4 = clampf(nv, 1e-8f, 5.f);
  float ke2 = tanhf(kSqrtC * nc4) / (kSqrtC * nc4);
  float rn2 = sqrtf(ke2 * ke2 * sv + 1e-15f);
  float sc2 = rn2 > kMaxNorm ? kMaxNorm / rn2 : 1.f;
#pragma unroll
  for (int j = 0; j < 3; j++)
    outh[(size_t)r * D_MODEL + dd[j]] = ke2 * sc2 * v[j];
}

// --- residual accumulate + hyp_layernorm, one wave per row (no barriers) ----
__global__ __launch_bounds__(256) void k_resln(
    const float* __restrict__ hid, const float* __restrict__ res_in,
    float* __restrict__ res_out, const float* __restrict__ g_,
    const float* __restrict__ b_, u16* __restrict__ out_bf,
    float* __restrict__ out_f, int first, int out_logmap) {
  const int lane = threadIdx.x & 63;
  const int r = blockIdx.x * 4 + (threadIdx.x >> 6);
  float v[6];
  int dd[6];
#pragma unroll
  for (int j = 0; j < 6; j++) {
    dd[j] = lane + j * 64;
    size_t idx = (size_t)r * D_MODEL + dd[j];
    v[j] = hid[idx] + (first ? 0.f : res_in[idx]);
    res_out[idx] = v[j];
  }
  float ss = 0.f;
#pragma unroll
  for (int j = 0; j < 6; j++) ss += v[j] * v[j];
  float s = waveSum(ss);
  float n = sqrtf(s + 1e-15f);
  float nc = clampf(n, 1e-8f, kMaxNorm);
  float kl = fatanh(fminf(kSqrtC * nc, 0.95f)) / (kSqrtC * nc);
  float t[6];
  float ts = 0.f;
#pragma unroll
  for (int j = 0; j < 6; j++) { t[j] = kl * v[j]; ts += t[j]; }
  float mean = waveSum(ts) * (1.f / 384.f);
  float dv = 0.f;
#pragma unroll
  for (int j = 0; j < 6; j++) { float d = t[j] - mean; dv += d * d; }
  float var = waveSum(dv) * (1.f / 383.f);
  float inv = 1.f / (sqrtf(var) + 1e-5f);
  float g[6];
  float gs = 0.f;
#pragma unroll
  for (int j = 0; j < 6; j++) {
    g[j] = (t[j] - mean) * inv * g_[dd[j]] + b_[dd[j]];
    gs += g[j] * g[j];
  }
  float sg = waveSum(gs);
  float ng = sqrtf(sg + 1e-15f);
  float nc2 = clampf(ng, 1e-8f, 5.f);
  float ke = ftanh(kSqrtC * nc2) / (kSqrtC * nc2);
  float rn = sqrtf(ke * ke * sg + 1e-15f);
  float sc = rn > kMaxNorm ? kMaxNorm / rn : 1.f;
  float kk = ke * sc;
  if (!out_logmap) {
#pragma unroll
    for (int j = 0; j < 6; j++)
      out_bf[(size_t)r * D_MODEL + dd[j]] = f2bf(kk * g[j]);
  } else {
    float s2 = kk * kk * sg;
    float n3 = sqrtf(s2 + 1e-15f);
    float nc3 = clampf(n3, 1e-8f, kMaxNorm);
    float kl2 = fatanh(fminf(kSqrtC * nc3, 0.95f)) / (kSqrtC * nc3);
#pragma unroll
    for (int j = 0; j < 6; j++)
      out_f[(size_t)r * D_MODEL + dd[j]] = kl2 * kk * g[j];
  }
}

// -- conv1d(k=4, causal) + SiLU, tiled; writes u transposed AND normal -------
// Reads the x-half buffer xc [r][768].
__global__ __launch_bounds__(256) void k_convt(const u16* __restrict__ xc,
                                               const float* __restrict__ cw,
                                               const float* __restrict__ cb,
                                               u16* __restrict__ ut,
                                               u16* __restrict__ un) {
  __shared__ u16 sx[52][68];
  __shared__ u16 su2[49][68];
  const int d0 = blockIdx.x * 64;
  const int l0 = blockIdx.y * 49;
  const int b = blockIdx.z;
  const int t = threadIdx.x;
#pragma unroll
  for (int i = 0; i < 4; i++) {
    int idx = t + i * 256;
    if (idx < 832) {
      int row = idx >> 4, seg = idx & 15;
      int l = l0 - 3 + row;
      short4 v = {0, 0, 0, 0};
      if (l >= 0) {
        const u16* p = xc + (size_t)(b * LTOK + l) * D_INNER + d0 + seg * 4;
        v = *(const short4*)p;
      }
      *(short4*)&sx[row][seg * 4] = v;
    }
  }
  __syncthreads();
  const int dl = t & 63, lg = t >> 6;
  const int d = d0 + dl;
  const float c0 = cw[d * 4], c1 = cw[d * 4 + 1], c2 = cw[d * 4 + 2],
              c3 = cw[d * 4 + 3];
  const float bb = cb[d];
  for (int l = lg; l < 49; l += 4) {
    float acc = bb;
    acc = fmaf(c0, bf2f(sx[l + 0][dl]), acc);
    acc = fmaf(c1, bf2f(sx[l + 1][dl]), acc);
    acc = fmaf(c2, bf2f(sx[l + 2][dl]), acc);
    acc = fmaf(c3, bf2f(sx[l + 3][dl]), acc);
    su2[l][dl] = f2bf(fsilu(acc));
  }
  __syncthreads();
#pragma unroll
  for (int i = 0; i < 13; i++) {
    int idx = t + i * 256;
    if (idx < 3136) {
      int d_ = idx / 49, l_ = idx % 49;
      ut[(size_t)(d0 + d_) * NROW + b * LTOK + l0 + l_] = su2[l_][d_];
    }
  }
#pragma unroll
  for (int i = 0; i < 13; i++) {
    int idx = t + i * 256;
    if (idx < 3136) {
      int l_ = idx >> 6, d_ = idx & 63;
      un[(size_t)(b * LTOK + l0 + l_) * D_INNER + d0 + d_] = su2[l_][d_];
    }
  }
}

// ---------- parallel selective scan v9: 2 barriers, wave-local n-reduce -----
// One block per (d-group of 4, b). Thread (c = t&15, n = t>>4); c<14 active.
// Wave w holds n = 4w..4w+3; the sum over a wave's 4 n's is done in-register
// via shfl_xor(16/32); only the 4-way cross-wave sum goes through LDS
// (wsum[g][w][l]). All 4 g's run barrier-free; ONE barrier before the final
// reduce. Summation over n becomes pairwise-tree (f32 reorder, invisible
// under bf16 output rounding).
__global__ __launch_bounds__(256) void k_pscan(
    const u16* __restrict__ ut, const float* __restrict__ dblt,
    const float* __restrict__ dt_w, const float* __restrict__ dt_bias,
    const float* __restrict__ A_log, const float* __restrict__ Dp,
    const u16* __restrict__ zt, u16* __restrict__ yf) {
  __shared__ float sdt[4][196];
  __shared__ float su[4][196];
  __shared__ float wsum[4][4][196];
  const int d0 = blockIdx.x * 4, b = blockIdx.y;
  const int t = threadIdx.x;
  const size_t col0 = (size_t)b * LTOK;
  u16 zz[4] = {0, 0, 0, 0};
  if (t < 196) {
    float r[DT_RANK];
#pragma unroll
    for (int k = 0; k < DT_RANK; k++)
      r[k] = dblt[(size_t)k * NROW + col0 + t];
#pragma unroll
    for (int g = 0; g < 4; g++) {
      const int d = d0 + g;
      float acc = dt_bias[d];
#pragma unroll
      for (int k = 0; k < DT_RANK; k++)
        acc = fmaf(r[k], dt_w[d * DT_RANK + k], acc);
      sdt[g][t] = fsoftplus(acc);
      su[g][t] = bf2f(ut[(size_t)d * NROW + col0 + t]);
      zz[g] = zt[(size_t)d * NROW + col0 + t];
    }
  }
  const int c = t & 15, n = t >> 4;
  const int wv = t >> 6;             // wave index 0..3
  const int nl = (t >> 4) & 3;       // n within wave
  const bool act = c < 14;
  float Breg[14], Creg[14];
  if (act) {
    const float2* Bp =
        (const float2*)(dblt + (size_t)(DT_RANK + n) * NROW + col0 + c * 14);
    const float2* Cp = (const float2*)(
        dblt + (size_t)(DT_RANK + D_STATE + n) * NROW + col0 + c * 14);
#pragma unroll
    for (int j = 0; j < 7; j++) {
      float2 bv = Bp[j], cv = Cp[j];
      Breg[2 * j] = bv.x; Breg[2 * j + 1] = bv.y;
      Creg[2 * j] = cv.x; Creg[2 * j + 1] = cv.y;
    }
  }
  __syncthreads();   // sdt/su ready for all waves
#pragma unroll
  for (int g = 0; g < 4; g++) {
    const int d = d0 + g;
    const float a = -__expf(A_log[(size_t)d * D_STATE + n]);
    float dA[14], hh[14];
    float A = 1.f, Bc = 0.f;
    if (act) {
      float h = 0.f, p = 1.f;
#pragma unroll
      for (int j = 0; j < 14; j++) {
        int l = c * 14 + j;
        float dtv = sdt[g][l];
        float e = __expf(dtv * a);
        h = fmaf(e, h, dtv * Breg[j] * su[g][l]);
        dA[j] = e;
        hh[j] = h;
        p *= e;
      }
      A = p;
      Bc = h;
    }
#pragma unroll
    for (int off = 1; off < 16; off <<= 1) {
      float pA = __shfl_up(A, off, 16);
      float pB = __shfl_up(Bc, off, 16);
      if (c >= off) {
        Bc = fmaf(A, pB, Bc);
        A *= pA;
      }
    }
    float h0 = __shfl_up(Bc, 1, 16);
    if (c == 0) h0 = 0.f;
    {
      float p = 1.f;
#pragma unroll
      for (int j = 0; j < 14; j++) {
        float v = 0.f;
        if (act) {
          p *= dA[j];
          v = fmaf(p, h0, hh[j]) * Creg[j];
        }
        // in-wave sum over the wave's 4 n's (pairwise tree)
        v += __shfl_xor(v, 16, 64);
        v += __shfl_xor(v, 32, 64);
        if (act && nl == 0) wsum[g][wv][c * 14 + j] = v;
      }
    }
  }
  __syncthreads();   // all wsum written
  if (t < 196) {
    u16 og[4];
#pragma unroll
    for (int g = 0; g < 4; g++) {
      float y = wsum[g][0][t] + wsum[g][1][t] + wsum[g][2][t] + wsum[g][3][t];
      float yv = bf2f(f2bf(fmaf(Dp[d0 + g], su[g][t], y)));
      og[g] = f2bf(yv * bf2f(zz[g]));
    }
    short4 o4 = {(short)og[0], (short)og[1], (short)og[2], (short)og[3]};
    *(short4*)&yf[(col0 + t) * D_INNER + d0] = o4;
  }
}

// ---------------------- pool phase 1: partial sums over 14-token chunks -----
__global__ __launch_bounds__(128) void k_pool1(const float* __restrict__ tl,
                                               float* __restrict__ partial) {
  const int b = blockIdx.x, g = blockIdx.y, tid = threadIdx.x;
  float m[3] = {0.f, 0.f, 0.f};
  for (int l = g * 14; l < (g + 1) * 14; l++) {
    size_t row = ((size_t)b * LTOK + l) * D_MODEL;
#pragma unroll
    for (int j = 0; j < 3; j++) m[j] += tl[row + tid + j * 128];
  }
#pragma unroll
  for (int j = 0; j < 3; j++)
    partial[((size_t)b * 14 + g) * D_MODEL + tid + j * 128] = m[j];
}

// ------------------ pool phase 2: finalize mean + expmap0 -------------------
__global__ __launch_bounds__(128) void k_pool2(const float* __restrict__ partial,
                                               float* __restrict__ pooled,
                                               float* __restrict__ x2v) {
  __shared__ float sm[2];
  const int b = blockIdx.x, tid = threadIdx.x;
  float m[3] = {0.f, 0.f, 0.f};
  for (int g = 0; g < 14; g++) {
    size_t row = ((size_t)b * 14 + g) * D_MODEL;
#pragma unroll
    for (int j = 0; j < 3; j++) m[j] += partial[row + tid + j * 128];
  }
#pragma unroll
  for (int j = 0; j < 3; j++) m[j] *= (1.f / (float)LTOK);
  float s = blockSum128(m[0] * m[0] + m[1] * m[1] + m[2] * m[2], sm);
  float n = sqrtf(s + 1e-15f);
  float nc = clampf(n, 1e-8f, 5.f);
  float ke = tanhf(kSqrtC * nc) / (kSqrtC * nc);
  float rn = sqrtf(ke * ke * s + 1e-15f);
  float sc = rn > kMaxNorm ? kMaxNorm / rn : 1.f;
  float kk = ke * sc;
  float p[3];
#pragma unroll
  for (int j = 0; j < 3; j++) {
    p[j] = kk * m[j];
    pooled[(size_t)b * D_MODEL + tid + j * 128] = p[j];
  }
  float s2 = blockSum128(p[0] * p[0] + p[1] * p[1] + p[2] * p[2], sm);
  if (tid == 0) x2v[b] = s2;
}

// ------------------- hyperbolic distance head over prototypes ---------------
__global__ __launch_bounds__(256) void k_head(const float* __restrict__ pooled,
                                              const float* __restrict__ protos,
                                              const float* __restrict__ x2v,
                                              float* __restrict__ out) {
  __shared__ float sp[D_MODEL];
  const int b = blockIdx.y;
  const int c = blockIdx.x * 256 + threadIdx.x;
  for (int j = threadIdx.x; j < D_MODEL; j += 256)
    sp[j] = pooled[(size_t)b * D_MODEL + j];
  __syncthreads();
  if (c >= NCLS) return;
  const float* pr = protos + (size_t)c * D_MODEL;
  float dotv = 0.f, y2 = 0.f;
  for (int k = 0; k < D_MODEL; k++) {
    float w = pr[k];
    dotv += sp[k] * w;
    y2 += w * w;
  }
  float x2 = x2v[b];
  float xy = -dotv;
  float al = 1.f + xy + 0.5f * y2;
  float be = 1.f - 0.5f * x2;
  float num2 = al * al * x2 + 2.f * al * be * xy + be * be * y2;
  float den = fmaxf(1.f + xy + 0.25f * x2 * y2, 1e-15f);
  float r2 = num2 / (den * den) + 1e-15f;
  float dn = fminf(kSqrtC * sqrtf(r2), 1.f - 1e-5f);
  out[(size_t)b * NCLS + c] = -(2.f / kSqrtC) * atanhf(dn);
}

// ---------------------------------------------------------------------------
extern "C" void kernel_launch(void* const* d_in, const int* in_sizes, int n_in,
                              void* d_out, int out_size, void* d_ws,
                              size_t ws_size, hipStream_t stream) {
  const float* x        = (const float*)d_in[0];
  const float* patch_w  = (const float*)d_in[1];
  const float* patch_b  = (const float*)d_in[2];
  const float* hyp_w    = (const float*)d_in[3];
  const float* hyp_b    = (const float*)d_in[4];
  const float* pe_gamma = (const float*)d_in[5];
  const float* pe_beta  = (const float*)d_in[6];
  const float* pos      = (const float*)d_in[7];
  const float* in_w     = (const float*)d_in[8];
  const float* conv_w   = (const float*)d_in[9];
  const float* conv_b   = (const float*)d_in[10];
  const float* xp_w     = (const float*)d_in[11];
  const float* dt_w     = (const float*)d_in[12];
  const float* dt_bias  = (const float*)d_in[13];
  const float* A_log    = (const float*)d_in[14];
  const float* Dp       = (const float*)d_in[15];
  const float* out_w    = (const float*)d_in[16];
  const float* gamma    = (const float*)d_in[17];
  const float* beta     = (const float*)d_in[18];
  const float* gamma_f  = (const float*)d_in[19];
  const float* beta_f   = (const float*)d_in[20];
  const float* protos   = (const float*)d_in[21];
  float* out = (float*)d_out;

  // ---- workspace layout ----
  char* cur = (char*)d_ws;
  auto alloc = [&](size_t bytes) {
    char* p = cur;
    cur += (bytes + 255) & ~(size_t)255;
    return (void*)p;
  };
  float* hidden  = (float*)alloc((size_t)NROW * D_MODEL * 4);
  float* resid   = (float*)alloc((size_t)NROW * D_MODEL * 4);
  float* dblt    = (float*)alloc((size_t)64 * NROW * 4);   // dbl^T f32 (56 rows)
  float* fscr    = (float*)alloc((size_t)NROW * 768 * 4);  // stem/head scratch
  float* xn      = (float*)alloc((size_t)NROW * 4);
  float* pooled  = (float*)alloc((size_t)BSZ * D_MODEL * 4);
  float* x2v     = (float*)alloc((size_t)BSZ * 4);
  float* partial = (float*)alloc((size_t)BSZ * 14 * D_MODEL * 4);
  u16* hn_bf  = (u16*)alloc((size_t)NROW * D_MODEL * 2);
  u16* xc_bf  = (u16*)alloc((size_t)NROW * D_INNER * 2);       // in_proj x-half
  u16* zt     = (u16*)alloc((size_t)D_INNER * NROW * 2);       // z^T silu'd
  u16* ut     = (u16*)alloc((size_t)D_INNER * NROW * 2);       // u^T
  u16* u_bf   = (u16*)alloc((size_t)NROW * D_INNER * 2);       // u normal
  u16* yf     = (u16*)alloc((size_t)NROW * D_INNER * 2);       // gated y
  // bf16 weights
  const size_t n_inw  = (size_t)NDEPTH * 2 * D_INNER * D_MODEL;
  const size_t n_outw = (size_t)NDEPTH * D_MODEL * D_INNER;
  const size_t n_xpw  = (size_t)NDEPTH * NXP * D_INNER;
  const size_t n_pw   = (size_t)D_MODEL * 768;
  const size_t n_hw   = (size_t)D_MODEL * D_MODEL;
  u16* in_wb  = (u16*)alloc(n_inw * 2);
  u16* out_wb = (u16*)alloc(n_outw * 2);
  u16* xp_wb  = (u16*)alloc(n_xpw * 2);
  u16* p_wb   = (u16*)alloc(n_pw * 2);
  u16* h_wb   = (u16*)alloc(n_hw * 2);
  // stem/head aliases over dead regions (yf is layer-loop only)
  u16* P_bf     = yf;                               // 3136x768 bf16 im2col
  float* tokens = fscr;                             // 3136x384 f32
  float* mx     = fscr + (size_t)NROW * D_MODEL;    // 3136x384 f32
  float* hnf    = fscr;                             // head: f32 logmap rows

  // ---- weight conversion (single launch) ----
  {
    const int c0 = (int)(n_inw / 4), c1 = (int)(n_outw / 4),
              c2 = (int)(n_xpw / 4), c3 = (int)(n_pw / 4),
              c4 = (int)(n_hw / 4);
    const int tot = c0 + c1 + c2 + c3 + c4;
    k_cvt5<<<dim3((tot + 255) / 256), dim3(256), 0, stream>>>(
        in_w, in_wb, c0, out_w, out_wb, c1, xp_w, xp_wb, c2, patch_w, p_wb,
        c3, hyp_w, h_wb, c4);
  }

  // ---- stem ----
  k_im2col<<<dim3((NROW * 768) / 256), dim3(256), 0, stream>>>(x, P_bf);
  k_gemm_bb<<<dim3(NROW / 64, 6), dim3(256), 0, stream>>>(
      P_bf, p_wb, patch_b, tokens, nullptr, 768, 768, D_MODEL, 0, D_MODEL, 0,
      0, 0);
  k_stem_a<<<dim3(NROW), dim3(128), 0, stream>>>(tokens, hn_bf, xn);
  k_gemm_bb<<<dim3(NROW / 64, 6), dim3(256), 0, stream>>>(
      hn_bf, h_wb, nullptr, mx, nullptr, D_MODEL, D_MODEL, D_MODEL, 0, D_MODEL,
      0, 0, 0);
  k_stem_b<<<dim3(NROW), dim3(128), 0, stream>>>(mx, xn, hyp_b, pe_gamma,
                                                 pe_beta, pos, hidden);
  // ---- layers ----
  for (int i = 0; i < NDEPTH; i++) {
    k_resln<<<dim3(NROW / 4), dim3(256), 0, stream>>>(
        hidden, resid, resid, gamma + (size_t)i * D_MODEL,
        beta + (size_t)i * D_MODEL, hn_bf, nullptr, i == 0 ? 1 : 0, 0);
    // in_proj: x-half -> xc_bf rm; z-half silu'd -> zt transposed
    k_gemm_n128<<<dim3(NROW / 64, (2 * D_INNER) / 128), dim3(256), 0, stream>>>(
        hn_bf, in_wb + (size_t)i * 2 * D_INNER * D_MODEL, xc_bf, zt, D_MODEL,
        D_MODEL, D_INNER);
    // conv + silu -> ut (transposed) AND u_bf (normal)
    k_convt<<<dim3(12, 4, BSZ), dim3(256), 0, stream>>>(
        xc_bf, conv_w + (size_t)i * D_INNER * 4, conv_b + (size_t)i * D_INNER,
        ut, u_bf);
    // x_proj: A = u_bf (coalesced); out dblt f32 transposed ONLY
    k_gemm_bb<<<dim3(NROW / 64, 1), dim3(256), 0, stream>>>(
        u_bf, xp_wb + (size_t)i * NXP * D_INNER, nullptr, nullptr, dblt,
        D_INNER, D_INNER, 0, NROW, NXP, 0, 0, 0);
    // parallel scan v9 (2-barrier, wave-local n-reduce) -> yf [r, 768]
    k_pscan<<<dim3(D_INNER / 4, BSZ), dim3(256), 0, stream>>>(
        ut, dblt, dt_w + (size_t)i * D_INNER * DT_RANK,
        dt_bias + (size_t)i * D_INNER, A_log + (size_t)i * D_INNER * D_STATE,
        Dp + (size_t)i * D_INNER, zt, yf);
    k_gemm_bb<<<dim3(NROW / 64, 6), dim3(256), 0, stream>>>(
        yf, out_wb + (size_t)i * D_MODEL * D_INNER, nullptr, hidden, nullptr,
        D_INNER, D_INNER, D_MODEL, 0, D_MODEL, 0, 0, 0);
  }
  // ---- head ----
  k_resln<<<dim3(NROW / 4), dim3(256), 0, stream>>>(
      hidden, resid, resid, gamma_f, beta_f, nullptr, hnf, 0, 1);
  k_pool1<<<dim3(BSZ, 14), dim3(128), 0, stream>>>(hnf, partial);
  k_pool2<<<dim3(BSZ), dim3(128), 0, stream>>>(partial, pooled, x2v);
  k_head<<<dim3((NCLS + 255) / 256, BSZ), dim3(256), 0, stream>>>(pooled,
                                                                  protos, x2v,
                                                                  out);
}

// Round 9
// 2057.713 us; speedup vs baseline: 1.1521x; 1.1521x over previous
//
#include <hip/hip_runtime.h>
#include <hip/hip_bf16.h>
#include <math.h>

#define D_MODEL 384
#define D_INNER 768
#define D_STATE 16
#define DT_RANK 24
#define NXP 56          // DT_RANK + 2*D_STATE
#define LTOK 196
#define BSZ 16
#define NROW 3136       // BSZ * LTOK
#define NDEPTH 24
#define NCLS 1000

constexpr float kSqrtC   = 0.70710678118654752440f;
constexpr float kMaxNorm = 0.95f / 0.70710678118654752440f;   // 1.3435029...

typedef unsigned short u16;
typedef short  bf16x8 __attribute__((ext_vector_type(8)));
typedef u16    u16x8  __attribute__((ext_vector_type(8)));
typedef float  f32x4  __attribute__((ext_vector_type(4)));

__device__ __forceinline__ float clampf(float x, float lo, float hi) {
  return fminf(fmaxf(x, lo), hi);
}

// f32 -> bf16 (RNE)
__device__ __forceinline__ u16 f2bf(float f) {
  union { float f; unsigned u; } v; v.f = f;
  return (u16)((v.u + 0x7FFFu + ((v.u >> 16) & 1u)) >> 16);
}
// bf16 -> f32
__device__ __forceinline__ float bf2f(u16 s) {
  union { unsigned u; float f; } v; v.u = ((unsigned)s) << 16;
  return v.f;
}

// async global->LDS, 16 B per lane. LDS dest = wave-uniform base + lane*16.
__device__ __forceinline__ void gload16(const u16* g, u16* l) {
  __builtin_amdgcn_global_load_lds(
      (const __attribute__((address_space(1))) unsigned int*)g,
      (__attribute__((address_space(3))) unsigned int*)l, 16, 0, 0);
}

// ---- fast transcendentals (1e-7-ish rel err; invisible under bf16) --------
__device__ __forceinline__ float fsig(float x) {
  return __fdividef(1.f, 1.f + __expf(-x));
}
__device__ __forceinline__ float fsilu(float x) { return x * fsig(x); }
__device__ __forceinline__ float fsoftplus(float x) {
  return (x > 20.f) ? x : __logf(1.f + __expf(x));
}
__device__ __forceinline__ float ftanh(float x) {
  float e = __expf(2.f * x);
  return __fdividef(e - 1.f, e + 1.f);
}
__device__ __forceinline__ float fatanh(float x) {   // x in [0, 0.95]
  return 0.5f * __logf(__fdividef(1.f + x, 1.f - x));
}

// 64-lane wave reduction (no LDS, no barriers)
__device__ __forceinline__ float waveSum(float v) {
#pragma unroll
  for (int o = 1; o < 64; o <<= 1) v += __shfl_xor(v, o, 64);
  return v;
}

// block=128 sum-reduce with broadcast (stem kernels only).
__device__ __forceinline__ float blockSum128(float v, float* sm) {
#pragma unroll
  for (int o = 32; o > 0; o >>= 1) v += __shfl_down(v, o, 64);
  __syncthreads();
  if ((threadIdx.x & 63) == 0) sm[threadIdx.x >> 6] = v;
  __syncthreads();
  return sm[0] + sm[1];
}

// ----------------- f32 -> bf16 bulk convert, 5 tensors in one launch --------
__global__ __launch_bounds__(256) void k_cvt5(
    const float* __restrict__ s0, u16* __restrict__ d0, int n0,
    const float* __restrict__ s1, u16* __restrict__ d1, int n1,
    const float* __restrict__ s2, u16* __restrict__ d2, int n2,
    const float* __restrict__ s3, u16* __restrict__ d3, int n3,
    const float* __restrict__ s4, u16* __restrict__ d4, int n4) {
  int i = blockIdx.x * 256 + threadIdx.x;
  const float* s; u16* d;
  if (i < n0) { s = s0; d = d0; }
  else if ((i -= n0) < n1) { s = s1; d = d1; }
  else if ((i -= n1) < n2) { s = s2; d = d2; }
  else if ((i -= n2) < n3) { s = s3; d = d3; }
  else if ((i -= n3) < n4) { s = s4; d = d4; }
  else return;
  float4 v = ((const float4*)s)[i];
  short4 o = {(short)f2bf(v.x), (short)f2bf(v.y), (short)f2bf(v.z),
              (short)f2bf(v.w)};
  *(short4*)&d[(size_t)i * 4] = o;
}

// ------------------------------------------------- im2col (emit bf16) ------
__global__ __launch_bounds__(256) void k_im2col(const float* __restrict__ x,
                                                u16* __restrict__ P) {
  size_t idx = (size_t)blockIdx.x * 256 + threadIdx.x;
  if (idx >= (size_t)NROW * 768) return;
  int k = (int)(idx % 768);
  int r = (int)(idx / 768);
  int b = r / LTOK, t = r % LTOK;
  int hp = t / 14, wp = t % 14;
  int c = k / 256, rem = k % 256, i = rem / 16, j = rem % 16;
  P[idx] = f2bf(
      x[(((size_t)(b * 3 + c) * 224) + hp * 16 + i) * 224 + wp * 16 + j]);
}

// ------------------------- pure-bf16 MFMA GEMM 64x64: C = A*W^T (+b, act) ---
// A (M,K) bf16 rm stride lda. W (Nv,K) bf16 rm tight. REQUIRES K % 64 == 0.
// Double-buffered LDS, ONE barrier per K-step: stage(k+1) issued before
// compute(k), so global_load_lds overlaps ds_read+MFMA. XOR swizzle on both
// global source and ds_read. Rows >= Nv read garbage; their output columns
// are discarded.
__global__ __launch_bounds__(256) void k_gemm_bb(
    const u16* __restrict__ A, const u16* __restrict__ W,
    const float* __restrict__ bias, void* __restrict__ Cn,
    void* __restrict__ Ct, int K, int lda, int ldc, int ldct, int Nv, int act,
    int obf, int obf_t) {
  __shared__ u16 As[2][64 * 64];
  __shared__ u16 Ws[2][64 * 64];
  const int tid = threadIdx.x;
  const int m0 = blockIdx.x * 64;
  const int n0 = blockIdx.y * 64;
  const int lane = tid & 63;
  const int w = tid >> 6;
  const int wm = w & 1, wn = w >> 1;
  const int lm = lane & 15;
  const int quad = lane >> 4;
  const int r8 = lane >> 3;          // row within chunk, 0..7
  const int t8 = lane & 7;           // 16B slot within row
  const int gsg = t8 ^ r8;           // pre-swizzled global k-segment
  const int s = lm & 7;              // read-time swizzle

  f32x4 acc[2][2];
#pragma unroll
  for (int i = 0; i < 2; i++)
#pragma unroll
    for (int j = 0; j < 2; j++) acc[i][j] = (f32x4){0.f, 0.f, 0.f, 0.f};

  auto stage = [&](int buf, int k0) {
#pragma unroll
    for (int cc = 0; cc < 2; cc++) {
      const int c = 2 * w + cc;            // chunk 0..7 (wave-uniform)
      const int row = c * 8 + r8;
      gload16(A + (size_t)(m0 + row) * lda + k0 + gsg * 8, &As[buf][c * 512]);
      gload16(W + (size_t)(n0 + row) * K + k0 + gsg * 8, &Ws[buf][c * 512]);
    }
  };
  stage(0, 0);
  __syncthreads();
  int cur = 0;
  for (int k0 = 0; k0 < K; k0 += 64) {
    if (k0 + 64 < K) stage(cur ^ 1, k0 + 64);
#pragma unroll
    for (int h = 0; h < 2; h++) {
      const int col = (((h << 2) + quad) ^ s) << 3;
      bf16x8 af[2], bfr[2];
#pragma unroll
      for (int i = 0; i < 2; i++) {
        af[i]  = *(bf16x8*)&As[cur][(wm * 32 + i * 16 + lm) * 64 + col];
        bfr[i] = *(bf16x8*)&Ws[cur][(wn * 32 + i * 16 + lm) * 64 + col];
      }
#pragma unroll
      for (int i = 0; i < 2; i++)
#pragma unroll
        for (int j = 0; j < 2; j++)
          acc[i][j] = __builtin_amdgcn_mfma_f32_16x16x32_bf16(
              af[i], bfr[j], acc[i][j], 0, 0, 0);
    }
    __syncthreads();  // drains prefetch (vmcnt) + guards LDS reuse
    cur ^= 1;
  }
  // epilogue: C/D layout col=lane&15, row=quad*4+reg
#pragma unroll
  for (int i = 0; i < 2; i++) {
#pragma unroll
    for (int j = 0; j < 2; j++) {
      int cg = n0 + wn * 32 + j * 16 + lm;
      if (cg >= Nv) continue;
      float bj = bias ? bias[cg] : 0.f;
      float o[4];
      int rgb = m0 + wm * 32 + i * 16 + quad * 4;
#pragma unroll
      for (int reg = 0; reg < 4; reg++) {
        float v = acc[i][j][reg] + bj;
        if (act == 1) v = fsoftplus(v);
        else if (act == 2 && cg >= 768) v = fsilu(v);
        o[reg] = v;
      }
      if (Cn) {
#pragma unroll
        for (int reg = 0; reg < 4; reg++) {
          if (obf) ((u16*)Cn)[(size_t)(rgb + reg) * ldc + cg] = f2bf(o[reg]);
          else ((float*)Cn)[(size_t)(rgb + reg) * ldc + cg] = o[reg];
        }
      }
      if (Ct) {
        if (obf_t) {
          short4 o4 = {(short)f2bf(o[0]), (short)f2bf(o[1]), (short)f2bf(o[2]),
                       (short)f2bf(o[3])};
          *(short4*)&((u16*)Ct)[(size_t)cg * ldct + rgb] = o4;
        } else {
          float4 o4 = {o[0], o[1], o[2], o[3]};
          *(float4*)&((float*)Ct)[(size_t)cg * ldct + rgb] = o4;
        }
      }
    }
  }
}

// ----------- in_proj GEMM 64x128: x-half -> Cx rm [r][768], z-half ->
// silu'd TRANSPOSED Zt [768][NROW] (coalesced gate reads in pscan).
// K%64==0. Same double-buffered single-barrier pipeline.
__global__ __launch_bounds__(256) void k_gemm_n128(
    const u16* __restrict__ A, const u16* __restrict__ W,
    u16* __restrict__ Cx, u16* __restrict__ Zt, int K, int lda, int ldc) {
  __shared__ u16 As[2][64 * 64];
  __shared__ u16 Ws[2][128 * 64];
  const int tid = threadIdx.x;
  const int m0 = blockIdx.x * 64;
  const int n0 = blockIdx.y * 128;
  const int lane = tid & 63;
  const int w = tid >> 6;
  const int lm = lane & 15;
  const int quad = lane >> 4;
  const int r8 = lane >> 3;
  const int t8 = lane & 7;
  const int gsg = t8 ^ r8;
  const int s = lm & 7;

  f32x4 acc[4][2];
#pragma unroll
  for (int i = 0; i < 4; i++)
#pragma unroll
    for (int j = 0; j < 2; j++) acc[i][j] = (f32x4){0.f, 0.f, 0.f, 0.f};

  auto stage = [&](int buf, int k0) {
#pragma unroll
    for (int cc = 0; cc < 2; cc++) {
      const int c = 2 * w + cc;            // A chunks 0..7
      gload16(A + (size_t)(m0 + c * 8 + r8) * lda + k0 + gsg * 8,
              &As[buf][c * 512]);
    }
#pragma unroll
    for (int cc = 0; cc < 4; cc++) {
      const int c = 4 * w + cc;            // W chunks 0..15
      gload16(W + (size_t)(n0 + c * 8 + r8) * K + k0 + gsg * 8,
              &Ws[buf][c * 512]);
    }
  };
  stage(0, 0);
  __syncthreads();
  int cur = 0;
  for (int k0 = 0; k0 < K; k0 += 64) {
    if (k0 + 64 < K) stage(cur ^ 1, k0 + 64);
#pragma unroll
    for (int h = 0; h < 2; h++) {
      const int col = (((h << 2) + quad) ^ s) << 3;
      bf16x8 af[4], bfr[2];
#pragma unroll
      for (int i = 0; i < 4; i++)
        af[i] = *(bf16x8*)&As[cur][(i * 16 + lm) * 64 + col];
#pragma unroll
      for (int j = 0; j < 2; j++)
        bfr[j] = *(bf16x8*)&Ws[cur][(w * 32 + j * 16 + lm) * 64 + col];
#pragma unroll
      for (int i = 0; i < 4; i++)
#pragma unroll
        for (int j = 0; j < 2; j++)
          acc[i][j] = __builtin_amdgcn_mfma_f32_16x16x32_bf16(
              af[i], bfr[j], acc[i][j], 0, 0, 0);
    }
    __syncthreads();
    cur ^= 1;
  }
  // n0 is 0..767 (x-half) or 768..1535 (z-half) — never mixed (128 | 768).
#pragma unroll
  for (int i = 0; i < 4; i++) {
#pragma unroll
    for (int j = 0; j < 2; j++) {
      int cg = n0 + w * 32 + j * 16 + lm;
      int rgb = m0 + i * 16 + quad * 4;
      if (cg < 768) {
#pragma unroll
        for (int reg = 0; reg < 4; reg++)
          Cx[(size_t)(rgb + reg) * ldc + cg] = f2bf(acc[i][j][reg]);
      } else {
        short4 o4 = {(short)f2bf(fsilu(acc[i][j][0])),
                     (short)f2bf(fsilu(acc[i][j][1])),
                     (short)f2bf(fsilu(acc[i][j][2])),
                     (short)f2bf(fsilu(acc[i][j][3]))};
        *(short4*)&Zt[(size_t)(cg - 768) * NROW + rgb] = o4;
      }
    }
  }
}

// ------------------ stem a: expmap0(tokens) -> bf16 h + ||h|| ---------------
__global__ __launch_bounds__(128) void k_stem_a(const float* __restrict__ tok,
                                                u16* __restrict__ hb,
                                                float* __restrict__ xn) {
  __shared__ float sm[2];
  const int r = blockIdx.x, tid = threadIdx.x;
  float v[3];
#pragma unroll
  for (int j = 0; j < 3; j++) v[j] = tok[(size_t)r * D_MODEL + tid + j * 128];
  float s = blockSum128(v[0] * v[0] + v[1] * v[1] + v[2] * v[2], sm);
  float n = sqrtf(s + 1e-15f);
  float nc = clampf(n, 1e-8f, 5.f);
  float ke = tanhf(kSqrtC * nc) / (kSqrtC * nc);
  float rn = sqrtf(ke * ke * s + 1e-15f);
  float sc = rn > kMaxNorm ? kMaxNorm / rn : 1.f;
  float kk = ke * sc;
#pragma unroll
  for (int j = 0; j < 3; j++)
    hb[(size_t)r * D_MODEL + tid + j * 128] = f2bf(kk * v[j]);
  if (tid == 0) xn[r] = fmaxf(sqrtf(kk * kk * s + 1e-15f), 1e-8f);
}

// --- stem b: mobius_matvec tail + mobius_add(hyp_b) + hyp_LN + pos + expmap -
__global__ __launch_bounds__(128) void k_stem_b(
    const float* __restrict__ mx, const float* __restrict__ xn,
    const float* __restrict__ hyp_b, const float* __restrict__ pe_g,
    const float* __restrict__ pe_b, const float* __restrict__ pos,
    float* __restrict__ outh) {
  __shared__ float sm[2];
  const int r = blockIdx.x, tid = threadIdx.x;
  const int t = r % LTOK;
  float mv[3], bv[3];
  int dd[3];
#pragma unroll
  for (int j = 0; j < 3; j++) {
    dd[j] = tid + j * 128;
    mv[j] = mx[(size_t)r * D_MODEL + dd[j]];
    bv[j] = hyp_b[dd[j]];
  }
  float smx = blockSum128(mv[0] * mv[0] + mv[1] * mv[1] + mv[2] * mv[2], sm);
  float mxn = fmaxf(sqrtf(smx + 1e-15f), 1e-8f);
  float xnv = xn[r];
  float tt = tanhf(mxn / xnv * atanhf(fminf(kSqrtC * xnv, 1.f - 1e-5f)));
  float kres = tt / (mxn * kSqrtC);
  float res[3];
#pragma unroll
  for (int j = 0; j < 3; j++) res[j] = kres * mv[j];
  float xy = blockSum128(res[0] * bv[0] + res[1] * bv[1] + res[2] * bv[2], sm);
  float y2 = blockSum128(bv[0] * bv[0] + bv[1] * bv[1] + bv[2] * bv[2], sm);
  float x2 = kres * kres * smx;
  float al = 1.f + xy + 0.5f * y2;
  float be = 1.f - 0.5f * x2;
  float den = fmaxf(1.f + xy + 0.25f * x2 * y2, 1e-15f);
  float h1[3];
#pragma unroll
  for (int j = 0; j < 3; j++) h1[j] = (al * res[j] + be * bv[j]) / den;
  float s1 = blockSum128(h1[0] * h1[0] + h1[1] * h1[1] + h1[2] * h1[2], sm);
  float n1 = sqrtf(s1 + 1e-15f);
  float nc1 = clampf(n1, 1e-8f, kMaxNorm);
  float kl = atanhf(fminf(kSqrtC * nc1, 0.95f)) / (kSqrtC * nc1);
  float tl[3];
#pragma unroll
  for (int j = 0; j < 3; j++) tl[j] = kl * h1[j];
  float mean = blockSum128(tl[0] + tl[1] + tl[2], sm) * (1.f / 384.f);
  float dv = 0.f;
#pragma unroll
  for (int j = 0; j < 3; j++) { float d = tl[j] - mean; dv += d * d; }
  float var = blockSum128(dv, sm) * (1.f / 383.f);
  float inv = 1.f / (sqrtf(var) + 1e-5f);
  float g[3];
#pragma unroll
  for (int j = 0; j < 3; j++)
    g[j] = (tl[j] - mean) * inv * pe_g[dd[j]] + pe_b[dd[j]];
  float sg = blockSum128(g[0] * g[0] + g[1] * g[1] + g[2] * g[2], sm);
  float ng = sqrtf(sg + 1e-15f);
  float nc2 = clampf(ng, 1e-8f, 5.f);
  float ke = tanhf(kSqrtC * nc2) / (kSqrtC * nc2);
  float rn = sqrtf(ke * ke * sg + 1e-15f);
  float sc = rn > kMaxNorm ? kMaxNorm / rn : 1.f;
  float kk = ke * sc;
  float s2 = kk * kk * sg;
  float n3 = sqrtf(s2 + 1e-15f);
  float nc3 = clampf(n3, 1e-8f, kMaxNorm);
  float kl2 = atanhf(fminf(kSqrtC * nc3, 0.95f)) / (kSqrtC * nc3);
  float v[3];
#pragma unroll
  for (int j = 0; j < 3; j++)
    v[j] = kl2 * kk * g[j] + pos[(size_t)t * D_MODEL + dd[j]];
  float sv = blockSum128(v[0] * v[0] + v[1] * v[1] + v[2] * v[2], sm);
  float nv = sqrtf(sv + 1e-15f);
  float nc4 = clampf(nv, 1e-8f, 5.f);
  float ke2 = tanhf(kSqrtC * nc4) / (kSqrtC * nc4);
  float rn2 = sqrtf(ke2 * ke2 * sv + 1e-15f);
  float sc2 = rn2 > kMaxNorm ? kMaxNorm / rn2 : 1.f;
#pragma unroll
  for (int j = 0; j < 3; j++)
    outh[(size_t)r * D_MODEL + dd[j]] = ke2 * sc2 * v[j];
}

// --- residual accumulate + hyp_layernorm, one wave per row (no barriers) ----
__global__ __launch_bounds__(256) void k_resln(
    const float* __restrict__ hid, const float* __restrict__ res_in,
    float* __restrict__ res_out, const float* __restrict__ g_,
    const float* __restrict__ b_, u16* __restrict__ out_bf,
    float* __restrict__ out_f, int first, int out_logmap) {
  const int lane = threadIdx.x & 63;
  const int r = blockIdx.x * 4 + (threadIdx.x >> 6);
  float v[6];
  int dd[6];
#pragma unroll
  for (int j = 0; j < 6; j++) {
    dd[j] = lane + j * 64;
    size_t idx = (size_t)r * D_MODEL + dd[j];
    v[j] = hid[idx] + (first ? 0.f : res_in[idx]);
    res_out[idx] = v[j];
  }
  float ss = 0.f;
#pragma unroll
  for (int j = 0; j < 6; j++) ss += v[j] * v[j];
  float s = waveSum(ss);
  float n = sqrtf(s + 1e-15f);
  float nc = clampf(n, 1e-8f, kMaxNorm);
  float kl = fatanh(fminf(kSqrtC * nc, 0.95f)) / (kSqrtC * nc);
  float t[6];
  float ts = 0.f;
#pragma unroll
  for (int j = 0; j < 6; j++) { t[j] = kl * v[j]; ts += t[j]; }
  float mean = waveSum(ts) * (1.f / 384.f);
  float dv = 0.f;
#pragma unroll
  for (int j = 0; j < 6; j++) { float d = t[j] - mean; dv += d * d; }
  float var = waveSum(dv) * (1.f / 383.f);
  float inv = 1.f / (sqrtf(var) + 1e-5f);
  float g[6];
  float gs = 0.f;
#pragma unroll
  for (int j = 0; j < 6; j++) {
    g[j] = (t[j] - mean) * inv * g_[dd[j]] + b_[dd[j]];
    gs += g[j] * g[j];
  }
  float sg = waveSum(gs);
  float ng = sqrtf(sg + 1e-15f);
  float nc2 = clampf(ng, 1e-8f, 5.f);
  float ke = ftanh(kSqrtC * nc2) / (kSqrtC * nc2);
  float rn = sqrtf(ke * ke * sg + 1e-15f);
  float sc = rn > kMaxNorm ? kMaxNorm / rn : 1.f;
  float kk = ke * sc;
  if (!out_logmap) {
#pragma unroll
    for (int j = 0; j < 6; j++)
      out_bf[(size_t)r * D_MODEL + dd[j]] = f2bf(kk * g[j]);
  } else {
    float s2 = kk * kk * sg;
    float n3 = sqrtf(s2 + 1e-15f);
    float nc3 = clampf(n3, 1e-8f, kMaxNorm);
    float kl2 = fatanh(fminf(kSqrtC * nc3, 0.95f)) / (kSqrtC * nc3);
#pragma unroll
    for (int j = 0; j < 6; j++)
      out_f[(size_t)r * D_MODEL + dd[j]] = kl2 * kk * g[j];
  }
}

// -- conv1d(k=4, causal) + SiLU, tiled; writes u transposed AND normal -------
// Reads the x-half buffer xc [r][768].
__global__ __launch_bounds__(256) void k_convt(const u16* __restrict__ xc,
                                               const float* __restrict__ cw,
                                               const float* __restrict__ cb,
                                               u16* __restrict__ ut,
                                               u16* __restrict__ un) {
  __shared__ u16 sx[52][68];
  __shared__ u16 su2[49][68];
  const int d0 = blockIdx.x * 64;
  const int l0 = blockIdx.y * 49;
  const int b = blockIdx.z;
  const int t = threadIdx.x;
#pragma unroll
  for (int i = 0; i < 4; i++) {
    int idx = t + i * 256;
    if (idx < 832) {
      int row = idx >> 4, seg = idx & 15;
      int l = l0 - 3 + row;
      short4 v = {0, 0, 0, 0};
      if (l >= 0) {
        const u16* p = xc + (size_t)(b * LTOK + l) * D_INNER + d0 + seg * 4;
        v = *(const short4*)p;
      }
      *(short4*)&sx[row][seg * 4] = v;
    }
  }
  __syncthreads();
  const int dl = t & 63, lg = t >> 6;
  const int d = d0 + dl;
  const float c0 = cw[d * 4], c1 = cw[d * 4 + 1], c2 = cw[d * 4 + 2],
              c3 = cw[d * 4 + 3];
  const float bb = cb[d];
  for (int l = lg; l < 49; l += 4) {
    float acc = bb;
    acc = fmaf(c0, bf2f(sx[l + 0][dl]), acc);
    acc = fmaf(c1, bf2f(sx[l + 1][dl]), acc);
    acc = fmaf(c2, bf2f(sx[l + 2][dl]), acc);
    acc = fmaf(c3, bf2f(sx[l + 3][dl]), acc);
    su2[l][dl] = f2bf(fsilu(acc));
  }
  __syncthreads();
#pragma unroll
  for (int i = 0; i < 13; i++) {
    int idx = t + i * 256;
    if (idx < 3136) {
      int d_ = idx / 49, l_ = idx % 49;
      ut[(size_t)(d0 + d_) * NROW + b * LTOK + l0 + l_] = su2[l_][d_];
    }
  }
#pragma unroll
  for (int i = 0; i < 13; i++) {
    int idx = t + i * 256;
    if (idx < 3136) {
      int l_ = idx >> 6, d_ = idx & 63;
      un[(size_t)(b * LTOK + l0 + l_) * D_INNER + d0 + d_] = su2[l_][d_];
    }
  }
}

// ---------- parallel selective scan v10: v8 dataflow + ping-pong sprod ------
// One block per (d-group of 4, b). Thread (c = t&15, n = t>>4); c<14 active.
// dblt rows 0..23 = dt_r (f32), 24..39 = B, 40..55 = C.
// u from ut [d][r], gate z from zt [d][r] (both coalesced). Arithmetic is
// bit-identical to v8 (R7); only barriers change: sprod is double-buffered
// so each g needs ONE barrier (write buf[g&1] -> barrier -> reduce-read,
// while next g computes into the other buffer). buf[p] is not rewritten
// until one full barrier after its readers ran -> hazard-free. 5 barriers
// total vs v8's 9.
__global__ __launch_bounds__(256) void k_pscan(
    const u16* __restrict__ ut, const float* __restrict__ dblt,
    const float* __restrict__ dt_w, const float* __restrict__ dt_bias,
    const float* __restrict__ A_log, const float* __restrict__ Dp,
    const u16* __restrict__ zt, u16* __restrict__ yf) {
  __shared__ float sdt[4][196];
  __shared__ float su[4][196];
  __shared__ float sprod[2][16][197];
  const int d0 = blockIdx.x * 4, b = blockIdx.y;
  const int t = threadIdx.x;
  const size_t col0 = (size_t)b * LTOK;
  u16 zz[4] = {0, 0, 0, 0};
  if (t < 196) {
    float r[DT_RANK];
#pragma unroll
    for (int k = 0; k < DT_RANK; k++)
      r[k] = dblt[(size_t)k * NROW + col0 + t];
#pragma unroll
    for (int g = 0; g < 4; g++) {
      const int d = d0 + g;
      float acc = dt_bias[d];
#pragma unroll
      for (int k = 0; k < DT_RANK; k++)
        acc = fmaf(r[k], dt_w[d * DT_RANK + k], acc);
      sdt[g][t] = fsoftplus(acc);
      su[g][t] = bf2f(ut[(size_t)d * NROW + col0 + t]);
      zz[g] = zt[(size_t)d * NROW + col0 + t];
    }
  }
  const int c = t & 15, n = t >> 4;
  const bool act = c < 14;
  float Breg[14], Creg[14];
  if (act) {
    const float2* Bp =
        (const float2*)(dblt + (size_t)(DT_RANK + n) * NROW + col0 + c * 14);
    const float2* Cp = (const float2*)(
        dblt + (size_t)(DT_RANK + D_STATE + n) * NROW + col0 + c * 14);
#pragma unroll
    for (int j = 0; j < 7; j++) {
      float2 bv = Bp[j], cv = Cp[j];
      Breg[2 * j] = bv.x; Breg[2 * j + 1] = bv.y;
      Creg[2 * j] = cv.x; Creg[2 * j + 1] = cv.y;
    }
  }
  __syncthreads();   // sdt/su ready for all waves
  u16 og[4];
#pragma unroll
  for (int g = 0; g < 4; g++) {
    const int d = d0 + g;
    const float a = -__expf(A_log[(size_t)d * D_STATE + n]);
    float dA[14], hh[14];
    float A = 1.f, Bc = 0.f;
    if (act) {
      float h = 0.f, p = 1.f;
#pragma unroll
      for (int j = 0; j < 14; j++) {
        int l = c * 14 + j;
        float dtv = sdt[g][l];
        float e = __expf(dtv * a);
        h = fmaf(e, h, dtv * Breg[j] * su[g][l]);
        dA[j] = e;
        hh[j] = h;
        p *= e;
      }
      A = p;
      Bc = h;
    }
#pragma unroll
    for (int off = 1; off < 16; off <<= 1) {
      float pA = __shfl_up(A, off, 16);
      float pB = __shfl_up(Bc, off, 16);
      if (c >= off) {
        Bc = fmaf(A, pB, Bc);
        A *= pA;
      }
    }
    float h0 = __shfl_up(Bc, 1, 16);
    if (c == 0) h0 = 0.f;
    if (act) {
      float p = 1.f;
#pragma unroll
      for (int j = 0; j < 14; j++) {
        p *= dA[j];
        sprod[g & 1][n][c * 14 + j] = fmaf(p, h0, hh[j]) * Creg[j];
      }
    }
    __syncthreads();   // sprod[g&1] complete; also fences reuse at g+2
    if (t < 196) {
      float y = 0.f;
#pragma unroll
      for (int nn = 0; nn < 16; nn++) y += sprod[g & 1][nn][t];
      float yv = bf2f(f2bf(fmaf(Dp[d], su[g][t], y)));
      og[g] = f2bf(yv * bf2f(zz[g]));
    }
  }
  if (t < 196) {
    short4 o4 = {(short)og[0], (short)og[1], (short)og[2], (short)og[3]};
    *(short4*)&yf[(col0 + t) * D_INNER + d0] = o4;
  }
}

// ---------------------- pool phase 1: partial sums over 14-token chunks -----
__global__ __launch_bounds__(128) void k_pool1(const float* __restrict__ tl,
                                               float* __restrict__ partial) {
  const int b = blockIdx.x, g = blockIdx.y, tid = threadIdx.x;
  float m[3] = {0.f, 0.f, 0.f};
  for (int l = g * 14; l < (g + 1) * 14; l++) {
    size_t row = ((size_t)b * LTOK + l) * D_MODEL;
#pragma unroll
    for (int j = 0; j < 3; j++) m[j] += tl[row + tid + j * 128];
  }
#pragma unroll
  for (int j = 0; j < 3; j++)
    partial[((size_t)b * 14 + g) * D_MODEL + tid + j * 128] = m[j];
}

// ------------------ pool phase 2: finalize mean + expmap0 -------------------
__global__ __launch_bounds__(128) void k_pool2(const float* __restrict__ partial,
                                               float* __restrict__ pooled,
                                               float* __restrict__ x2v) {
  __shared__ float sm[2];
  const int b = blockIdx.x, tid = threadIdx.x;
  float m[3] = {0.f, 0.f, 0.f};
  for (int g = 0; g < 14; g++) {
    size_t row = ((size_t)b * 14 + g) * D_MODEL;
#pragma unroll
    for (int j = 0; j < 3; j++) m[j] += partial[row + tid + j * 128];
  }
#pragma unroll
  for (int j = 0; j < 3; j++) m[j] *= (1.f / (float)LTOK);
  float s = blockSum128(m[0] * m[0] + m[1] * m[1] + m[2] * m[2], sm);
  float n = sqrtf(s + 1e-15f);
  float nc = clampf(n, 1e-8f, 5.f);
  float ke = tanhf(kSqrtC * nc) / (kSqrtC * nc);
  float rn = sqrtf(ke * ke * s + 1e-15f);
  float sc = rn > kMaxNorm ? kMaxNorm / rn : 1.f;
  float kk = ke * sc;
  float p[3];
#pragma unroll
  for (int j = 0; j < 3; j++) {
    p[j] = kk * m[j];
    pooled[(size_t)b * D_MODEL + tid + j * 128] = p[j];
  }
  float s2 = blockSum128(p[0] * p[0] + p[1] * p[1] + p[2] * p[2], sm);
  if (tid == 0) x2v[b] = s2;
}

// ------------------- hyperbolic distance head over prototypes ---------------
__global__ __launch_bounds__(256) void k_head(const float* __restrict__ pooled,
                                              const float* __restrict__ protos,
                                              const float* __restrict__ x2v,
                                              float* __restrict__ out) {
  __shared__ float sp[D_MODEL];
  const int b = blockIdx.y;
  const int c = blockIdx.x * 256 + threadIdx.x;
  for (int j = threadIdx.x; j < D_MODEL; j += 256)
    sp[j] = pooled[(size_t)b * D_MODEL + j];
  __syncthreads();
  if (c >= NCLS) return;
  const float* pr = protos + (size_t)c * D_MODEL;
  float dotv = 0.f, y2 = 0.f;
  for (int k = 0; k < D_MODEL; k++) {
    float w = pr[k];
    dotv += sp[k] * w;
    y2 += w * w;
  }
  float x2 = x2v[b];
  float xy = -dotv;
  float al = 1.f + xy + 0.5f * y2;
  float be = 1.f - 0.5f * x2;
  float num2 = al * al * x2 + 2.f * al * be * xy + be * be * y2;
  float den = fmaxf(1.f + xy + 0.25f * x2 * y2, 1e-15f);
  float r2 = num2 / (den * den) + 1e-15f;
  float dn = fminf(kSqrtC * sqrtf(r2), 1.f - 1e-5f);
  out[(size_t)b * NCLS + c] = -(2.f / kSqrtC) * atanhf(dn);
}

// ---------------------------------------------------------------------------
extern "C" void kernel_launch(void* const* d_in, const int* in_sizes, int n_in,
                              void* d_out, int out_size, void* d_ws,
                              size_t ws_size, hipStream_t stream) {
  const float* x        = (const float*)d_in[0];
  const float* patch_w  = (const float*)d_in[1];
  const float* patch_b  = (const float*)d_in[2];
  const float* hyp_w    = (const float*)d_in[3];
  const float* hyp_b    = (const float*)d_in[4];
  const float* pe_gamma = (const float*)d_in[5];
  const float* pe_beta  = (const float*)d_in[6];
  const float* pos      = (const float*)d_in[7];
  const float* in_w     = (const float*)d_in[8];
  const float* conv_w   = (const float*)d_in[9];
  const float* conv_b   = (const float*)d_in[10];
  const float* xp_w     = (const float*)d_in[11];
  const float* dt_w     = (const float*)d_in[12];
  const float* dt_bias  = (const float*)d_in[13];
  const float* A_log    = (const float*)d_in[14];
  const float* Dp       = (const float*)d_in[15];
  const float* out_w    = (const float*)d_in[16];
  const float* gamma    = (const float*)d_in[17];
  const float* beta     = (const float*)d_in[18];
  const float* gamma_f  = (const float*)d_in[19];
  const float* beta_f   = (const float*)d_in[20];
  const float* protos   = (const float*)d_in[21];
  float* out = (float*)d_out;

  // ---- workspace layout ----
  char* cur = (char*)d_ws;
  auto alloc = [&](size_t bytes) {
    char* p = cur;
    cur += (bytes + 255) & ~(size_t)255;
    return (void*)p;
  };
  float* hidden  = (float*)alloc((size_t)NROW * D_MODEL * 4);
  float* resid   = (float*)alloc((size_t)NROW * D_MODEL * 4);
  float* dblt    = (float*)alloc((size_t)64 * NROW * 4);   // dbl^T f32 (56 rows)
  float* fscr    = (float*)alloc((size_t)NROW * 768 * 4);  // stem/head scratch
  float* xn      = (float*)alloc((size_t)NROW * 4);
  float* pooled  = (float*)alloc((size_t)BSZ * D_MODEL * 4);
  float* x2v     = (float*)alloc((size_t)BSZ * 4);
  float* partial = (float*)alloc((size_t)BSZ * 14 * D_MODEL * 4);
  u16* hn_bf  = (u16*)alloc((size_t)NROW * D_MODEL * 2);
  u16* xc_bf  = (u16*)alloc((size_t)NROW * D_INNER * 2);       // in_proj x-half
  u16* zt     = (u16*)alloc((size_t)D_INNER * NROW * 2);       // z^T silu'd
  u16* ut     = (u16*)alloc((size_t)D_INNER * NROW * 2);       // u^T
  u16* u_bf   = (u16*)alloc((size_t)NROW * D_INNER * 2);       // u normal
  u16* yf     = (u16*)alloc((size_t)NROW * D_INNER * 2);       // gated y
  // bf16 weights
  const size_t n_inw  = (size_t)NDEPTH * 2 * D_INNER * D_MODEL;
  const size_t n_outw = (size_t)NDEPTH * D_MODEL * D_INNER;
  const size_t n_xpw  = (size_t)NDEPTH * NXP * D_INNER;
  const size_t n_pw   = (size_t)D_MODEL * 768;
  const size_t n_hw   = (size_t)D_MODEL * D_MODEL;
  u16* in_wb  = (u16*)alloc(n_inw * 2);
  u16* out_wb = (u16*)alloc(n_outw * 2);
  u16* xp_wb  = (u16*)alloc(n_xpw * 2);
  u16* p_wb   = (u16*)alloc(n_pw * 2);
  u16* h_wb   = (u16*)alloc(n_hw * 2);
  // stem/head aliases over dead regions (yf is layer-loop only)
  u16* P_bf     = yf;                               // 3136x768 bf16 im2col
  float* tokens = fscr;                             // 3136x384 f32
  float* mx     = fscr + (size_t)NROW * D_MODEL;    // 3136x384 f32
  float* hnf    = fscr;                             // head: f32 logmap rows

  // ---- weight conversion (single launch) ----
  {
    const int c0 = (int)(n_inw / 4), c1 = (int)(n_outw / 4),
              c2 = (int)(n_xpw / 4), c3 = (int)(n_pw / 4),
              c4 = (int)(n_hw / 4);
    const int tot = c0 + c1 + c2 + c3 + c4;
    k_cvt5<<<dim3((tot + 255) / 256), dim3(256), 0, stream>>>(
        in_w, in_wb, c0, out_w, out_wb, c1, xp_w, xp_wb, c2, patch_w, p_wb,
        c3, hyp_w, h_wb, c4);
  }

  // ---- stem ----
  k_im2col<<<dim3((NROW * 768) / 256), dim3(256), 0, stream>>>(x, P_bf);
  k_gemm_bb<<<dim3(NROW / 64, 6), dim3(256), 0, stream>>>(
      P_bf, p_wb, patch_b, tokens, nullptr, 768, 768, D_MODEL, 0, D_MODEL, 0,
      0, 0);
  k_stem_a<<<dim3(NROW), dim3(128), 0, stream>>>(tokens, hn_bf, xn);
  k_gemm_bb<<<dim3(NROW / 64, 6), dim3(256), 0, stream>>>(
      hn_bf, h_wb, nullptr, mx, nullptr, D_MODEL, D_MODEL, D_MODEL, 0, D_MODEL,
      0, 0, 0);
  k_stem_b<<<dim3(NROW), dim3(128), 0, stream>>>(mx, xn, hyp_b, pe_gamma,
                                                 pe_beta, pos, hidden);
  // ---- layers ----
  for (int i = 0; i < NDEPTH; i++) {
    k_resln<<<dim3(NROW / 4), dim3(256), 0, stream>>>(
        hidden, resid, resid, gamma + (size_t)i * D_MODEL,
        beta + (size_t)i * D_MODEL, hn_bf, nullptr, i == 0 ? 1 : 0, 0);
    // in_proj: x-half -> xc_bf rm; z-half silu'd -> zt transposed
    k_gemm_n128<<<dim3(NROW / 64, (2 * D_INNER) / 128), dim3(256), 0, stream>>>(
        hn_bf, in_wb + (size_t)i * 2 * D_INNER * D_MODEL, xc_bf, zt, D_MODEL,
        D_MODEL, D_INNER);
    // conv + silu -> ut (transposed) AND u_bf (normal)
    k_convt<<<dim3(12, 4, BSZ), dim3(256), 0, stream>>>(
        xc_bf, conv_w + (size_t)i * D_INNER * 4, conv_b + (size_t)i * D_INNER,
        ut, u_bf);
    // x_proj: A = u_bf (coalesced); out dblt f32 transposed ONLY
    k_gemm_bb<<<dim3(NROW / 64, 1), dim3(256), 0, stream>>>(
        u_bf, xp_wb + (size_t)i * NXP * D_INNER, nullptr, nullptr, dblt,
        D_INNER, D_INNER, 0, NROW, NXP, 0, 0, 0);
    // parallel scan v10 (v8 dataflow, ping-pong sprod) -> yf [r, 768]
    k_pscan<<<dim3(D_INNER / 4, BSZ), dim3(256), 0, stream>>>(
        ut, dblt, dt_w + (size_t)i * D_INNER * DT_RANK,
        dt_bias + (size_t)i * D_INNER, A_log + (size_t)i * D_INNER * D_STATE,
        Dp + (size_t)i * D_INNER, zt, yf);
    k_gemm_bb<<<dim3(NROW / 64, 6), dim3(256), 0, stream>>>(
        yf, out_wb + (size_t)i * D_MODEL * D_INNER, nullptr, hidden, nullptr,
        D_INNER, D_INNER, D_MODEL, 0, D_MODEL, 0, 0, 0);
  }
  // ---- head ----
  k_resln<<<dim3(NROW / 4), dim3(256), 0, stream>>>(
      hidden, resid, resid, gamma_f, beta_f, nullptr, hnf, 0, 1);
  k_pool1<<<dim3(BSZ, 14), dim3(128), 0, stream>>>(hnf, partial);
  k_pool2<<<dim3(BSZ), dim3(128), 0, stream>>>(partial, pooled, x2v);
  k_head<<<dim3((NCLS + 255) / 256, BSZ), dim3(256), 0, stream>>>(pooled,
                                                                  protos, x2v,
                                                                  out);
}

// Round 10
// 2037.268 us; speedup vs baseline: 1.1636x; 1.0100x over previous
//
#include <hip/hip_runtime.h>
#include <hip/hip_bf16.h>
#include <math.h>

#define D_MODEL 384
#define D_INNER 768
#define D_STATE 16
#define DT_RANK 24
#define NXP 56          // DT_RANK + 2*D_STATE
#define LTOK 196
#define BSZ 16
#define NROW 3136       // BSZ * LTOK
#define NDEPTH 24
#define NCLS 1000

constexpr float kSqrtC   = 0.70710678118654752440f;
constexpr float kMaxNorm = 0.95f / 0.70710678118654752440f;   // 1.3435029...

typedef unsigned short u16;
typedef short  bf16x8 __attribute__((ext_vector_type(8)));
typedef u16    u16x8  __attribute__((ext_vector_type(8)));
typedef float  f32x4  __attribute__((ext_vector_type(4)));

__device__ __forceinline__ float clampf(float x, float lo, float hi) {
  return fminf(fmaxf(x, lo), hi);
}

// f32 -> bf16 (RNE)
__device__ __forceinline__ u16 f2bf(float f) {
  union { float f; unsigned u; } v; v.f = f;
  return (u16)((v.u + 0x7FFFu + ((v.u >> 16) & 1u)) >> 16);
}
// bf16 -> f32
__device__ __forceinline__ float bf2f(u16 s) {
  union { unsigned u; float f; } v; v.u = ((unsigned)s) << 16;
  return v.f;
}

// async global->LDS, 16 B per lane. LDS dest = wave-uniform base + lane*16.
__device__ __forceinline__ void gload16(const u16* g, u16* l) {
  __builtin_amdgcn_global_load_lds(
      (const __attribute__((address_space(1))) unsigned int*)g,
      (__attribute__((address_space(3))) unsigned int*)l, 16, 0, 0);
}

// ---- fast transcendentals (1e-7-ish rel err; invisible under bf16) --------
__device__ __forceinline__ float fsig(float x) {
  return __fdividef(1.f, 1.f + __expf(-x));
}
__device__ __forceinline__ float fsilu(float x) { return x * fsig(x); }
__device__ __forceinline__ float fsoftplus(float x) {
  return (x > 20.f) ? x : __logf(1.f + __expf(x));
}
__device__ __forceinline__ float ftanh(float x) {
  float e = __expf(2.f * x);
  return __fdividef(e - 1.f, e + 1.f);
}
__device__ __forceinline__ float fatanh(float x) {   // x in [0, 0.95]
  return 0.5f * __logf(__fdividef(1.f + x, 1.f - x));
}

// 64-lane wave reduction (no LDS, no barriers)
__device__ __forceinline__ float waveSum(float v) {
#pragma unroll
  for (int o = 1; o < 64; o <<= 1) v += __shfl_xor(v, o, 64);
  return v;
}

// block=128 sum-reduce with broadcast (stem kernels only).
__device__ __forceinline__ float blockSum128(float v, float* sm) {
#pragma unroll
  for (int o = 32; o > 0; o >>= 1) v += __shfl_down(v, o, 64);
  __syncthreads();
  if ((threadIdx.x & 63) == 0) sm[threadIdx.x >> 6] = v;
  __syncthreads();
  return sm[0] + sm[1];
}

// ----------------- f32 -> bf16 bulk convert, 5 tensors in one launch --------
__global__ __launch_bounds__(256) void k_cvt5(
    const float* __restrict__ s0, u16* __restrict__ d0, int n0,
    const float* __restrict__ s1, u16* __restrict__ d1, int n1,
    const float* __restrict__ s2, u16* __restrict__ d2, int n2,
    const float* __restrict__ s3, u16* __restrict__ d3, int n3,
    const float* __restrict__ s4, u16* __restrict__ d4, int n4) {
  int i = blockIdx.x * 256 + threadIdx.x;
  const float* s; u16* d;
  if (i < n0) { s = s0; d = d0; }
  else if ((i -= n0) < n1) { s = s1; d = d1; }
  else if ((i -= n1) < n2) { s = s2; d = d2; }
  else if ((i -= n2) < n3) { s = s3; d = d3; }
  else if ((i -= n3) < n4) { s = s4; d = d4; }
  else return;
  float4 v = ((const float4*)s)[i];
  short4 o = {(short)f2bf(v.x), (short)f2bf(v.y), (short)f2bf(v.z),
              (short)f2bf(v.w)};
  *(short4*)&d[(size_t)i * 4] = o;
}

// ------------------------------------------------- im2col (emit bf16) ------
__global__ __launch_bounds__(256) void k_im2col(const float* __restrict__ x,
                                                u16* __restrict__ P) {
  size_t idx = (size_t)blockIdx.x * 256 + threadIdx.x;
  if (idx >= (size_t)NROW * 768) return;
  int k = (int)(idx % 768);
  int r = (int)(idx / 768);
  int b = r / LTOK, t = r % LTOK;
  int hp = t / 14, wp = t % 14;
  int c = k / 256, rem = k % 256, i = rem / 16, j = rem % 16;
  P[idx] = f2bf(
      x[(((size_t)(b * 3 + c) * 224) + hp * 16 + i) * 224 + wp * 16 + j]);
}

// ------------------------- pure-bf16 MFMA GEMM 64x64: C = A*W^T (+b, act) ---
// A (M,K) bf16 rm stride lda. W (Nv,K) bf16 rm tight. REQUIRES K % 64 == 0.
// Double-buffered LDS, ONE barrier per K-step: stage(k+1) issued before
// compute(k), so global_load_lds overlaps ds_read+MFMA. XOR swizzle on both
// global source and ds_read. Rows >= Nv read garbage; their output columns
// are discarded.
__global__ __launch_bounds__(256) void k_gemm_bb(
    const u16* __restrict__ A, const u16* __restrict__ W,
    const float* __restrict__ bias, void* __restrict__ Cn,
    void* __restrict__ Ct, int K, int lda, int ldc, int ldct, int Nv, int act,
    int obf, int obf_t) {
  __shared__ u16 As[2][64 * 64];
  __shared__ u16 Ws[2][64 * 64];
  const int tid = threadIdx.x;
  const int m0 = blockIdx.x * 64;
  const int n0 = blockIdx.y * 64;
  const int lane = tid & 63;
  const int w = tid >> 6;
  const int wm = w & 1, wn = w >> 1;
  const int lm = lane & 15;
  const int quad = lane >> 4;
  const int r8 = lane >> 3;          // row within chunk, 0..7
  const int t8 = lane & 7;           // 16B slot within row
  const int gsg = t8 ^ r8;           // pre-swizzled global k-segment
  const int s = lm & 7;              // read-time swizzle

  f32x4 acc[2][2];
#pragma unroll
  for (int i = 0; i < 2; i++)
#pragma unroll
    for (int j = 0; j < 2; j++) acc[i][j] = (f32x4){0.f, 0.f, 0.f, 0.f};

  auto stage = [&](int buf, int k0) {
#pragma unroll
    for (int cc = 0; cc < 2; cc++) {
      const int c = 2 * w + cc;            // chunk 0..7 (wave-uniform)
      const int row = c * 8 + r8;
      gload16(A + (size_t)(m0 + row) * lda + k0 + gsg * 8, &As[buf][c * 512]);
      gload16(W + (size_t)(n0 + row) * K + k0 + gsg * 8, &Ws[buf][c * 512]);
    }
  };
  stage(0, 0);
  __syncthreads();
  int cur = 0;
  for (int k0 = 0; k0 < K; k0 += 64) {
    if (k0 + 64 < K) stage(cur ^ 1, k0 + 64);
#pragma unroll
    for (int h = 0; h < 2; h++) {
      const int col = (((h << 2) + quad) ^ s) << 3;
      bf16x8 af[2], bfr[2];
#pragma unroll
      for (int i = 0; i < 2; i++) {
        af[i]  = *(bf16x8*)&As[cur][(wm * 32 + i * 16 + lm) * 64 + col];
        bfr[i] = *(bf16x8*)&Ws[cur][(wn * 32 + i * 16 + lm) * 64 + col];
      }
#pragma unroll
      for (int i = 0; i < 2; i++)
#pragma unroll
        for (int j = 0; j < 2; j++)
          acc[i][j] = __builtin_amdgcn_mfma_f32_16x16x32_bf16(
              af[i], bfr[j], acc[i][j], 0, 0, 0);
    }
    __syncthreads();  // drains prefetch (vmcnt) + guards LDS reuse
    cur ^= 1;
  }
  // epilogue: C/D layout col=lane&15, row=quad*4+reg
#pragma unroll
  for (int i = 0; i < 2; i++) {
#pragma unroll
    for (int j = 0; j < 2; j++) {
      int cg = n0 + wn * 32 + j * 16 + lm;
      if (cg >= Nv) continue;
      float bj = bias ? bias[cg] : 0.f;
      float o[4];
      int rgb = m0 + wm * 32 + i * 16 + quad * 4;
#pragma unroll
      for (int reg = 0; reg < 4; reg++) {
        float v = acc[i][j][reg] + bj;
        if (act == 1) v = fsoftplus(v);
        else if (act == 2 && cg >= 768) v = fsilu(v);
        o[reg] = v;
      }
      if (Cn) {
#pragma unroll
        for (int reg = 0; reg < 4; reg++) {
          if (obf) ((u16*)Cn)[(size_t)(rgb + reg) * ldc + cg] = f2bf(o[reg]);
          else ((float*)Cn)[(size_t)(rgb + reg) * ldc + cg] = o[reg];
        }
      }
      if (Ct) {
        if (obf_t) {
          short4 o4 = {(short)f2bf(o[0]), (short)f2bf(o[1]), (short)f2bf(o[2]),
                       (short)f2bf(o[3])};
          *(short4*)&((u16*)Ct)[(size_t)cg * ldct + rgb] = o4;
        } else {
          float4 o4 = {o[0], o[1], o[2], o[3]};
          *(float4*)&((float*)Ct)[(size_t)cg * ldct + rgb] = o4;
        }
      }
    }
  }
}

// ----------- in_proj GEMM 64x128: x-half -> Cx rm [r][768], z-half ->
// silu'd TRANSPOSED Zt [768][NROW] (coalesced gate reads in pscan).
// K%64==0. Same double-buffered single-barrier pipeline.
__global__ __launch_bounds__(256) void k_gemm_n128(
    const u16* __restrict__ A, const u16* __restrict__ W,
    u16* __restrict__ Cx, u16* __restrict__ Zt, int K, int lda, int ldc) {
  __shared__ u16 As[2][64 * 64];
  __shared__ u16 Ws[2][128 * 64];
  const int tid = threadIdx.x;
  const int m0 = blockIdx.x * 64;
  const int n0 = blockIdx.y * 128;
  const int lane = tid & 63;
  const int w = tid >> 6;
  const int lm = lane & 15;
  const int quad = lane >> 4;
  const int r8 = lane >> 3;
  const int t8 = lane & 7;
  const int gsg = t8 ^ r8;
  const int s = lm & 7;

  f32x4 acc[4][2];
#pragma unroll
  for (int i = 0; i < 4; i++)
#pragma unroll
    for (int j = 0; j < 2; j++) acc[i][j] = (f32x4){0.f, 0.f, 0.f, 0.f};

  auto stage = [&](int buf, int k0) {
#pragma unroll
    for (int cc = 0; cc < 2; cc++) {
      const int c = 2 * w + cc;            // A chunks 0..7
      gload16(A + (size_t)(m0 + c * 8 + r8) * lda + k0 + gsg * 8,
              &As[buf][c * 512]);
    }
#pragma unroll
    for (int cc = 0; cc < 4; cc++) {
      const int c = 4 * w + cc;            // W chunks 0..15
      gload16(W + (size_t)(n0 + c * 8 + r8) * K + k0 + gsg * 8,
              &Ws[buf][c * 512]);
    }
  };
  stage(0, 0);
  __syncthreads();
  int cur = 0;
  for (int k0 = 0; k0 < K; k0 += 64) {
    if (k0 + 64 < K) stage(cur ^ 1, k0 + 64);
#pragma unroll
    for (int h = 0; h < 2; h++) {
      const int col = (((h << 2) + quad) ^ s) << 3;
      bf16x8 af[4], bfr[2];
#pragma unroll
      for (int i = 0; i < 4; i++)
        af[i] = *(bf16x8*)&As[cur][(i * 16 + lm) * 64 + col];
#pragma unroll
      for (int j = 0; j < 2; j++)
        bfr[j] = *(bf16x8*)&Ws[cur][(w * 32 + j * 16 + lm) * 64 + col];
#pragma unroll
      for (int i = 0; i < 4; i++)
#pragma unroll
        for (int j = 0; j < 2; j++)
          acc[i][j] = __builtin_amdgcn_mfma_f32_16x16x32_bf16(
              af[i], bfr[j], acc[i][j], 0, 0, 0);
    }
    __syncthreads();
    cur ^= 1;
  }
  // n0 is 0..767 (x-half) or 768..1535 (z-half) — never mixed (128 | 768).
#pragma unroll
  for (int i = 0; i < 4; i++) {
#pragma unroll
    for (int j = 0; j < 2; j++) {
      int cg = n0 + w * 32 + j * 16 + lm;
      int rgb = m0 + i * 16 + quad * 4;
      if (cg < 768) {
#pragma unroll
        for (int reg = 0; reg < 4; reg++)
          Cx[(size_t)(rgb + reg) * ldc + cg] = f2bf(acc[i][j][reg]);
      } else {
        short4 o4 = {(short)f2bf(fsilu(acc[i][j][0])),
                     (short)f2bf(fsilu(acc[i][j][1])),
                     (short)f2bf(fsilu(acc[i][j][2])),
                     (short)f2bf(fsilu(acc[i][j][3]))};
        *(short4*)&Zt[(size_t)(cg - 768) * NROW + rgb] = o4;
      }
    }
  }
}

// ------------------ stem a: expmap0(tokens) -> bf16 h + ||h|| ---------------
__global__ __launch_bounds__(128) void k_stem_a(const float* __restrict__ tok,
                                                u16* __restrict__ hb,
                                                float* __restrict__ xn) {
  __shared__ float sm[2];
  const int r = blockIdx.x, tid = threadIdx.x;
  float v[3];
#pragma unroll
  for (int j = 0; j < 3; j++) v[j] = tok[(size_t)r * D_MODEL + tid + j * 128];
  float s = blockSum128(v[0] * v[0] + v[1] * v[1] + v[2] * v[2], sm);
  float n = sqrtf(s + 1e-15f);
  float nc = clampf(n, 1e-8f, 5.f);
  float ke = tanhf(kSqrtC * nc) / (kSqrtC * nc);
  float rn = sqrtf(ke * ke * s + 1e-15f);
  float sc = rn > kMaxNorm ? kMaxNorm / rn : 1.f;
  float kk = ke * sc;
#pragma unroll
  for (int j = 0; j < 3; j++)
    hb[(size_t)r * D_MODEL + tid + j * 128] = f2bf(kk * v[j]);
  if (tid == 0) xn[r] = fmaxf(sqrtf(kk * kk * s + 1e-15f), 1e-8f);
}

// --- stem b: mobius_matvec tail + mobius_add(hyp_b) + hyp_LN + pos + expmap -
__global__ __launch_bounds__(128) void k_stem_b(
    const float* __restrict__ mx, const float* __restrict__ xn,
    const float* __restrict__ hyp_b, const float* __restrict__ pe_g,
    const float* __restrict__ pe_b, const float* __restrict__ pos,
    float* __restrict__ outh) {
  __shared__ float sm[2];
  const int r = blockIdx.x, tid = threadIdx.x;
  const int t = r % LTOK;
  float mv[3], bv[3];
  int dd[3];
#pragma unroll
  for (int j = 0; j < 3; j++) {
    dd[j] = tid + j * 128;
    mv[j] = mx[(size_t)r * D_MODEL + dd[j]];
    bv[j] = hyp_b[dd[j]];
  }
  float smx = blockSum128(mv[0] * mv[0] + mv[1] * mv[1] + mv[2] * mv[2], sm);
  float mxn = fmaxf(sqrtf(smx + 1e-15f), 1e-8f);
  float xnv = xn[r];
  float tt = tanhf(mxn / xnv * atanhf(fminf(kSqrtC * xnv, 1.f - 1e-5f)));
  float kres = tt / (mxn * kSqrtC);
  float res[3];
#pragma unroll
  for (int j = 0; j < 3; j++) res[j] = kres * mv[j];
  float xy = blockSum128(res[0] * bv[0] + res[1] * bv[1] + res[2] * bv[2], sm);
  float y2 = blockSum128(bv[0] * bv[0] + bv[1] * bv[1] + bv[2] * bv[2], sm);
  float x2 = kres * kres * smx;
  float al = 1.f + xy + 0.5f * y2;
  float be = 1.f - 0.5f * x2;
  float den = fmaxf(1.f + xy + 0.25f * x2 * y2, 1e-15f);
  float h1[3];
#pragma unroll
  for (int j = 0; j < 3; j++) h1[j] = (al * res[j] + be * bv[j]) / den;
  float s1 = blockSum128(h1[0] * h1[0] + h1[1] * h1[1] + h1[2] * h1[2], sm);
  float n1 = sqrtf(s1 + 1e-15f);
  float nc1 = clampf(n1, 1e-8f, kMaxNorm);
  float kl = atanhf(fminf(kSqrtC * nc1, 0.95f)) / (kSqrtC * nc1);
  float tl[3];
#pragma unroll
  for (int j = 0; j < 3; j++) tl[j] = kl * h1[j];
  float mean = blockSum128(tl[0] + tl[1] + tl[2], sm) * (1.f / 384.f);
  float dv = 0.f;
#pragma unroll
  for (int j = 0; j < 3; j++) { float d = tl[j] - mean; dv += d * d; }
  float var = blockSum128(dv, sm) * (1.f / 383.f);
  float inv = 1.f / (sqrtf(var) + 1e-5f);
  float g[3];
#pragma unroll
  for (int j = 0; j < 3; j++)
    g[j] = (tl[j] - mean) * inv * pe_g[dd[j]] + pe_b[dd[j]];
  float sg = blockSum128(g[0] * g[0] + g[1] * g[1] + g[2] * g[2], sm);
  float ng = sqrtf(sg + 1e-15f);
  float nc2 = clampf(ng, 1e-8f, 5.f);
  float ke = tanhf(kSqrtC * nc2) / (kSqrtC * nc2);
  float rn = sqrtf(ke * ke * sg + 1e-15f);
  float sc = rn > kMaxNorm ? kMaxNorm / rn : 1.f;
  float kk = ke * sc;
  float s2 = kk * kk * sg;
  float n3 = sqrtf(s2 + 1e-15f);
  float nc3 = clampf(n3, 1e-8f, kMaxNorm);
  float kl2 = atanhf(fminf(kSqrtC * nc3, 0.95f)) / (kSqrtC * nc3);
  float v[3];
#pragma unroll
  for (int j = 0; j < 3; j++)
    v[j] = kl2 * kk * g[j] + pos[(size_t)t * D_MODEL + dd[j]];
  float sv = blockSum128(v[0] * v[0] + v[1] * v[1] + v[2] * v[2], sm);
  float nv = sqrtf(sv + 1e-15f);
  float nc4 = clampf(nv, 1e-8f, 5.f);
  float ke2 = tanhf(kSqrtC * nc4) / (kSqrtC * nc4);
  float rn2 = sqrtf(ke2 * ke2 * sv + 1e-15f);
  float sc2 = rn2 > kMaxNorm ? kMaxNorm / rn2 : 1.f;
#pragma unroll
  for (int j = 0; j < 3; j++)
    outh[(size_t)r * D_MODEL + dd[j]] = ke2 * sc2 * v[j];
}

// --- residual accumulate + hyp_layernorm, one wave per row (no barriers) ----
__global__ __launch_bounds__(256) void k_resln(
    const float* __restrict__ hid, const float* __restrict__ res_in,
    float* __restrict__ res_out, const float* __restrict__ g_,
    const float* __restrict__ b_, u16* __restrict__ out_bf,
    float* __restrict__ out_f, int first, int out_logmap) {
  const int lane = threadIdx.x & 63;
  const int r = blockIdx.x * 4 + (threadIdx.x >> 6);
  float v[6];
  int dd[6];
#pragma unroll
  for (int j = 0; j < 6; j++) {
    dd[j] = lane + j * 64;
    size_t idx = (size_t)r * D_MODEL + dd[j];
    v[j] = hid[idx] + (first ? 0.f : res_in[idx]);
    res_out[idx] = v[j];
  }
  float ss = 0.f;
#pragma unroll
  for (int j = 0; j < 6; j++) ss += v[j] * v[j];
  float s = waveSum(ss);
  float n = sqrtf(s + 1e-15f);
  float nc = clampf(n, 1e-8f, kMaxNorm);
  float kl = fatanh(fminf(kSqrtC * nc, 0.95f)) / (kSqrtC * nc);
  float t[6];
  float ts = 0.f;
#pragma unroll
  for (int j = 0; j < 6; j++) { t[j] = kl * v[j]; ts += t[j]; }
  float mean = waveSum(ts) * (1.f / 384.f);
  float dv = 0.f;
#pragma unroll
  for (int j = 0; j < 6; j++) { float d = t[j] - mean; dv += d * d; }
  float var = waveSum(dv) * (1.f / 383.f);
  float inv = 1.f / (sqrtf(var) + 1e-5f);
  float g[6];
  float gs = 0.f;
#pragma unroll
  for (int j = 0; j < 6; j++) {
    g[j] = (t[j] - mean) * inv * g_[dd[j]] + b_[dd[j]];
    gs += g[j] * g[j];
  }
  float sg = waveSum(gs);
  float ng = sqrtf(sg + 1e-15f);
  float nc2 = clampf(ng, 1e-8f, 5.f);
  float ke = ftanh(kSqrtC * nc2) / (kSqrtC * nc2);
  float rn = sqrtf(ke * ke * sg + 1e-15f);
  float sc = rn > kMaxNorm ? kMaxNorm / rn : 1.f;
  float kk = ke * sc;
  if (!out_logmap) {
#pragma unroll
    for (int j = 0; j < 6; j++)
      out_bf[(size_t)r * D_MODEL + dd[j]] = f2bf(kk * g[j]);
  } else {
    float s2 = kk * kk * sg;
    float n3 = sqrtf(s2 + 1e-15f);
    float nc3 = clampf(n3, 1e-8f, kMaxNorm);
    float kl2 = fatanh(fminf(kSqrtC * nc3, 0.95f)) / (kSqrtC * nc3);
#pragma unroll
    for (int j = 0; j < 6; j++)
      out_f[(size_t)r * D_MODEL + dd[j]] = kl2 * kk * g[j];
  }
}

// -- conv1d(k=4, causal) + SiLU, tiled; writes u transposed AND normal -------
// Reads the x-half buffer xc [r][768].
__global__ __launch_bounds__(256) void k_convt(const u16* __restrict__ xc,
                                               const float* __restrict__ cw,
                                               const float* __restrict__ cb,
                                               u16* __restrict__ ut,
                                               u16* __restrict__ un) {
  __shared__ u16 sx[52][68];
  __shared__ u16 su2[49][68];
  const int d0 = blockIdx.x * 64;
  const int l0 = blockIdx.y * 49;
  const int b = blockIdx.z;
  const int t = threadIdx.x;
#pragma unroll
  for (int i = 0; i < 4; i++) {
    int idx = t + i * 256;
    if (idx < 832) {
      int row = idx >> 4, seg = idx & 15;
      int l = l0 - 3 + row;
      short4 v = {0, 0, 0, 0};
      if (l >= 0) {
        const u16* p = xc + (size_t)(b * LTOK + l) * D_INNER + d0 + seg * 4;
        v = *(const short4*)p;
      }
      *(short4*)&sx[row][seg * 4] = v;
    }
  }
  __syncthreads();
  const int dl = t & 63, lg = t >> 6;
  const int d = d0 + dl;
  const float c0 = cw[d * 4], c1 = cw[d * 4 + 1], c2 = cw[d * 4 + 2],
              c3 = cw[d * 4 + 3];
  const float bb = cb[d];
  for (int l = lg; l < 49; l += 4) {
    float acc = bb;
    acc = fmaf(c0, bf2f(sx[l + 0][dl]), acc);
    acc = fmaf(c1, bf2f(sx[l + 1][dl]), acc);
    acc = fmaf(c2, bf2f(sx[l + 2][dl]), acc);
    acc = fmaf(c3, bf2f(sx[l + 3][dl]), acc);
    su2[l][dl] = f2bf(fsilu(acc));
  }
  __syncthreads();
#pragma unroll
  for (int i = 0; i < 13; i++) {
    int idx = t + i * 256;
    if (idx < 3136) {
      int d_ = idx / 49, l_ = idx % 49;
      ut[(size_t)(d0 + d_) * NROW + b * LTOK + l0 + l_] = su2[l_][d_];
    }
  }
#pragma unroll
  for (int i = 0; i < 13; i++) {
    int idx = t + i * 256;
    if (idx < 3136) {
      int l_ = idx >> 6, d_ = idx & 63;
      un[(size_t)(b * LTOK + l0 + l_) * D_INNER + d0 + d_] = su2[l_][d_];
    }
  }
}

// ---------- parallel selective scan v11: LDS-op-lean (b64 packed) -----------
// One block per (d-group of 4, b). Thread (c = t&15, n = t>>4); c<14 active.
// dblt rows 0..23 = dt_r (f32), 24..39 = B, 40..55 = C.
// LDS-op reductions vs v8/v10 (arith BIT-IDENTICAL):
//  - dt & u packed in float2 sdu[g][l] -> chain reads are 14 b64 (not 28 b32)
//  - sprod flipped to [l][n] pad 18 -> reduce = 8 b64 reads (not 16 b32),
//    sum register order still n=0..15 sequential
//  - single sprod buffer, 26.6 KB LDS -> 6 blocks/CU
__global__ __launch_bounds__(256) void k_pscan(
    const u16* __restrict__ ut, const float* __restrict__ dblt,
    const float* __restrict__ dt_w, const float* __restrict__ dt_bias,
    const float* __restrict__ A_log, const float* __restrict__ Dp,
    const u16* __restrict__ zt, u16* __restrict__ yf) {
  __shared__ float2 sdu[4][196];        // {dt, u}
  __shared__ float sprod[196][18];      // [l][n], pad 18
  const int d0 = blockIdx.x * 4, b = blockIdx.y;
  const int t = threadIdx.x;
  const size_t col0 = (size_t)b * LTOK;
  u16 zz[4] = {0, 0, 0, 0};
  float uo[4];                           // u at l=t, for D*u epilogue
  if (t < 196) {
    float r[DT_RANK];
#pragma unroll
    for (int k = 0; k < DT_RANK; k++)
      r[k] = dblt[(size_t)k * NROW + col0 + t];
#pragma unroll
    for (int g = 0; g < 4; g++) {
      const int d = d0 + g;
      float acc = dt_bias[d];
#pragma unroll
      for (int k = 0; k < DT_RANK; k++)
        acc = fmaf(r[k], dt_w[d * DT_RANK + k], acc);
      float uv = bf2f(ut[(size_t)d * NROW + col0 + t]);
      sdu[g][t] = make_float2(fsoftplus(acc), uv);
      uo[g] = uv;
      zz[g] = zt[(size_t)d * NROW + col0 + t];
    }
  }
  const int c = t & 15, n = t >> 4;
  const bool act = c < 14;
  float Breg[14], Creg[14];
  if (act) {
    const float2* Bp =
        (const float2*)(dblt + (size_t)(DT_RANK + n) * NROW + col0 + c * 14);
    const float2* Cp = (const float2*)(
        dblt + (size_t)(DT_RANK + D_STATE + n) * NROW + col0 + c * 14);
#pragma unroll
    for (int j = 0; j < 7; j++) {
      float2 bv = Bp[j], cv = Cp[j];
      Breg[2 * j] = bv.x; Breg[2 * j + 1] = bv.y;
      Creg[2 * j] = cv.x; Creg[2 * j + 1] = cv.y;
    }
  }
  __syncthreads();   // sdu ready for all waves
  u16 og[4];
#pragma unroll
  for (int g = 0; g < 4; g++) {
    const int d = d0 + g;
    const float a = -__expf(A_log[(size_t)d * D_STATE + n]);
    float dA[14], hh[14];
    float A = 1.f, Bc = 0.f;
    if (act) {
      float2 du[14];
#pragma unroll
      for (int j = 0; j < 14; j++) du[j] = sdu[g][c * 14 + j];
      float h = 0.f, p = 1.f;
#pragma unroll
      for (int j = 0; j < 14; j++) {
        float dtv = du[j].x;
        float e = __expf(dtv * a);
        h = fmaf(e, h, dtv * Breg[j] * du[j].y);
        dA[j] = e;
        hh[j] = h;
        p *= e;
      }
      A = p;
      Bc = h;
    }
#pragma unroll
    for (int off = 1; off < 16; off <<= 1) {
      float pA = __shfl_up(A, off, 16);
      float pB = __shfl_up(Bc, off, 16);
      if (c >= off) {
        Bc = fmaf(A, pB, Bc);
        A *= pA;
      }
    }
    float h0 = __shfl_up(Bc, 1, 16);
    if (c == 0) h0 = 0.f;
    if (g > 0) __syncthreads();   // prev g's reduce reads done before rewrite
    if (act) {
      float p = 1.f;
#pragma unroll
      for (int j = 0; j < 14; j++) {
        p *= dA[j];
        sprod[c * 14 + j][n] = fmaf(p, h0, hh[j]) * Creg[j];
      }
    }
    __syncthreads();   // sprod complete
    if (t < 196) {
      float y = 0.f;
#pragma unroll
      for (int pp = 0; pp < 8; pp++) {
        float2 v = *(float2*)&sprod[t][2 * pp];
        y += v.x;          // n = 2*pp   (order preserved: n = 0..15)
        y += v.y;          // n = 2*pp+1
      }
      float yv = bf2f(f2bf(fmaf(Dp[d], uo[g], y)));
      og[g] = f2bf(yv * bf2f(zz[g]));
    }
  }
  if (t < 196) {
    short4 o4 = {(short)og[0], (short)og[1], (short)og[2], (short)og[3]};
    *(short4*)&yf[(col0 + t) * D_INNER + d0] = o4;
  }
}

// ---------------------- pool phase 1: partial sums over 14-token chunks -----
__global__ __launch_bounds__(128) void k_pool1(const float* __restrict__ tl,
                                               float* __restrict__ partial) {
  const int b = blockIdx.x, g = blockIdx.y, tid = threadIdx.x;
  float m[3] = {0.f, 0.f, 0.f};
  for (int l = g * 14; l < (g + 1) * 14; l++) {
    size_t row = ((size_t)b * LTOK + l) * D_MODEL;
#pragma unroll
    for (int j = 0; j < 3; j++) m[j] += tl[row + tid + j * 128];
  }
#pragma unroll
  for (int j = 0; j < 3; j++)
    partial[((size_t)b * 14 + g) * D_MODEL + tid + j * 128] = m[j];
}

// ------------------ pool phase 2: finalize mean + expmap0 -------------------
__global__ __launch_bounds__(128) void k_pool2(const float* __restrict__ partial,
                                               float* __restrict__ pooled,
                                               float* __restrict__ x2v) {
  __shared__ float sm[2];
  const int b = blockIdx.x, tid = threadIdx.x;
  float m[3] = {0.f, 0.f, 0.f};
  for (int g = 0; g < 14; g++) {
    size_t row = ((size_t)b * 14 + g) * D_MODEL;
#pragma unroll
    for (int j = 0; j < 3; j++) m[j] += partial[row + tid + j * 128];
  }
#pragma unroll
  for (int j = 0; j < 3; j++) m[j] *= (1.f / (float)LTOK);
  float s = blockSum128(m[0] * m[0] + m[1] * m[1] + m[2] * m[2], sm);
  float n = sqrtf(s + 1e-15f);
  float nc = clampf(n, 1e-8f, 5.f);
  float ke = tanhf(kSqrtC * nc) / (kSqrtC * nc);
  float rn = sqrtf(ke * ke * s + 1e-15f);
  float sc = rn > kMaxNorm ? kMaxNorm / rn : 1.f;
  float kk = ke * sc;
  float p[3];
#pragma unroll
  for (int j = 0; j < 3; j++) {
    p[j] = kk * m[j];
    pooled[(size_t)b * D_MODEL + tid + j * 128] = p[j];
  }
  float s2 = blockSum128(p[0] * p[0] + p[1] * p[1] + p[2] * p[2], sm);
  if (tid == 0) x2v[b] = s2;
}

// ------------------- hyperbolic distance head over prototypes ---------------
__global__ __launch_bounds__(256) void k_head(const float* __restrict__ pooled,
                                              const float* __restrict__ protos,
                                              const float* __restrict__ x2v,
                                              float* __restrict__ out) {
  __shared__ float sp[D_MODEL];
  const int b = blockIdx.y;
  const int c = blockIdx.x * 256 + threadIdx.x;
  for (int j = threadIdx.x; j < D_MODEL; j += 256)
    sp[j] = pooled[(size_t)b * D_MODEL + j];
  __syncthreads();
  if (c >= NCLS) return;
  const float* pr = protos + (size_t)c * D_MODEL;
  float dotv = 0.f, y2 = 0.f;
  for (int k = 0; k < D_MODEL; k++) {
    float w = pr[k];
    dotv += sp[k] * w;
    y2 += w * w;
  }
  float x2 = x2v[b];
  float xy = -dotv;
  float al = 1.f + xy + 0.5f * y2;
  float be = 1.f - 0.5f * x2;
  float num2 = al * al * x2 + 2.f * al * be * xy + be * be * y2;
  float den = fmaxf(1.f + xy + 0.25f * x2 * y2, 1e-15f);
  float r2 = num2 / (den * den) + 1e-15f;
  float dn = fminf(kSqrtC * sqrtf(r2), 1.f - 1e-5f);
  out[(size_t)b * NCLS + c] = -(2.f / kSqrtC) * atanhf(dn);
}

// ---------------------------------------------------------------------------
extern "C" void kernel_launch(void* const* d_in, const int* in_sizes, int n_in,
                              void* d_out, int out_size, void* d_ws,
                              size_t ws_size, hipStream_t stream) {
  const float* x        = (const float*)d_in[0];
  const float* patch_w  = (const float*)d_in[1];
  const float* patch_b  = (const float*)d_in[2];
  const float* hyp_w    = (const float*)d_in[3];
  const float* hyp_b    = (const float*)d_in[4];
  const float* pe_gamma = (const float*)d_in[5];
  const float* pe_beta  = (const float*)d_in[6];
  const float* pos      = (const float*)d_in[7];
  const float* in_w     = (const float*)d_in[8];
  const float* conv_w   = (const float*)d_in[9];
  const float* conv_b   = (const float*)d_in[10];
  const float* xp_w     = (const float*)d_in[11];
  const float* dt_w     = (const float*)d_in[12];
  const float* dt_bias  = (const float*)d_in[13];
  const float* A_log    = (const float*)d_in[14];
  const float* Dp       = (const float*)d_in[15];
  const float* out_w    = (const float*)d_in[16];
  const float* gamma    = (const float*)d_in[17];
  const float* beta     = (const float*)d_in[18];
  const float* gamma_f  = (const float*)d_in[19];
  const float* beta_f   = (const float*)d_in[20];
  const float* protos   = (const float*)d_in[21];
  float* out = (float*)d_out;

  // ---- workspace layout ----
  char* cur = (char*)d_ws;
  auto alloc = [&](size_t bytes) {
    char* p = cur;
    cur += (bytes + 255) & ~(size_t)255;
    return (void*)p;
  };
  float* hidden  = (float*)alloc((size_t)NROW * D_MODEL * 4);
  float* resid   = (float*)alloc((size_t)NROW * D_MODEL * 4);
  float* dblt    = (float*)alloc((size_t)64 * NROW * 4);   // dbl^T f32 (56 rows)
  float* fscr    = (float*)alloc((size_t)NROW * 768 * 4);  // stem/head scratch
  float* xn      = (float*)alloc((size_t)NROW * 4);
  float* pooled  = (float*)alloc((size_t)BSZ * D_MODEL * 4);
  float* x2v     = (float*)alloc((size_t)BSZ * 4);
  float* partial = (float*)alloc((size_t)BSZ * 14 * D_MODEL * 4);
  u16* hn_bf  = (u16*)alloc((size_t)NROW * D_MODEL * 2);
  u16* xc_bf  = (u16*)alloc((size_t)NROW * D_INNER * 2);       // in_proj x-half
  u16* zt     = (u16*)alloc((size_t)D_INNER * NROW * 2);       // z^T silu'd
  u16* ut     = (u16*)alloc((size_t)D_INNER * NROW * 2);       // u^T
  u16* u_bf   = (u16*)alloc((size_t)NROW * D_INNER * 2);       // u normal
  u16* yf     = (u16*)alloc((size_t)NROW * D_INNER * 2);       // gated y
  // bf16 weights
  const size_t n_inw  = (size_t)NDEPTH * 2 * D_INNER * D_MODEL;
  const size_t n_outw = (size_t)NDEPTH * D_MODEL * D_INNER;
  const size_t n_xpw  = (size_t)NDEPTH * NXP * D_INNER;
  const size_t n_pw   = (size_t)D_MODEL * 768;
  const size_t n_hw   = (size_t)D_MODEL * D_MODEL;
  u16* in_wb  = (u16*)alloc(n_inw * 2);
  u16* out_wb = (u16*)alloc(n_outw * 2);
  u16* xp_wb  = (u16*)alloc(n_xpw * 2);
  u16* p_wb   = (u16*)alloc(n_pw * 2);
  u16* h_wb   = (u16*)alloc(n_hw * 2);
  // stem/head aliases over dead regions (yf is layer-loop only)
  u16* P_bf     = yf;                               // 3136x768 bf16 im2col
  float* tokens = fscr;                             // 3136x384 f32
  float* mx     = fscr + (size_t)NROW * D_MODEL;    // 3136x384 f32
  float* hnf    = fscr;                             // head: f32 logmap rows

  // ---- weight conversion (single launch) ----
  {
    const int c0 = (int)(n_inw / 4), c1 = (int)(n_outw / 4),
              c2 = (int)(n_xpw / 4), c3 = (int)(n_pw / 4),
              c4 = (int)(n_hw / 4);
    const int tot = c0 + c1 + c2 + c3 + c4;
    k_cvt5<<<dim3((tot + 255) / 256), dim3(256), 0, stream>>>(
        in_w, in_wb, c0, out_w, out_wb, c1, xp_w, xp_wb, c2, patch_w, p_wb,
        c3, hyp_w, h_wb, c4);
  }

  // ---- stem ----
  k_im2col<<<dim3((NROW * 768) / 256), dim3(256), 0, stream>>>(x, P_bf);
  k_gemm_bb<<<dim3(NROW / 64, 6), dim3(256), 0, stream>>>(
      P_bf, p_wb, patch_b, tokens, nullptr, 768, 768, D_MODEL, 0, D_MODEL, 0,
      0, 0);
  k_stem_a<<<dim3(NROW), dim3(128), 0, stream>>>(tokens, hn_bf, xn);
  k_gemm_bb<<<dim3(NROW / 64, 6), dim3(256), 0, stream>>>(
      hn_bf, h_wb, nullptr, mx, nullptr, D_MODEL, D_MODEL, D_MODEL, 0, D_MODEL,
      0, 0, 0);
  k_stem_b<<<dim3(NROW), dim3(128), 0, stream>>>(mx, xn, hyp_b, pe_gamma,
                                                 pe_beta, pos, hidden);
  // ---- layers ----
  for (int i = 0; i < NDEPTH; i++) {
    k_resln<<<dim3(NROW / 4), dim3(256), 0, stream>>>(
        hidden, resid, resid, gamma + (size_t)i * D_MODEL,
        beta + (size_t)i * D_MODEL, hn_bf, nullptr, i == 0 ? 1 : 0, 0);
    // in_proj: x-half -> xc_bf rm; z-half silu'd -> zt transposed
    k_gemm_n128<<<dim3(NROW / 64, (2 * D_INNER) / 128), dim3(256), 0, stream>>>(
        hn_bf, in_wb + (size_t)i * 2 * D_INNER * D_MODEL, xc_bf, zt, D_MODEL,
        D_MODEL, D_INNER);
    // conv + silu -> ut (transposed) AND u_bf (normal)
    k_convt<<<dim3(12, 4, BSZ), dim3(256), 0, stream>>>(
        xc_bf, conv_w + (size_t)i * D_INNER * 4, conv_b + (size_t)i * D_INNER,
        ut, u_bf);
    // x_proj: A = u_bf (coalesced); out dblt f32 transposed ONLY
    k_gemm_bb<<<dim3(NROW / 64, 1), dim3(256), 0, stream>>>(
        u_bf, xp_wb + (size_t)i * NXP * D_INNER, nullptr, nullptr, dblt,
        D_INNER, D_INNER, 0, NROW, NXP, 0, 0, 0);
    // parallel scan v11 (b64-packed LDS, [l][n] sprod) -> yf [r, 768]
    k_pscan<<<dim3(D_INNER / 4, BSZ), dim3(256), 0, stream>>>(
        ut, dblt, dt_w + (size_t)i * D_INNER * DT_RANK,
        dt_bias + (size_t)i * D_INNER, A_log + (size_t)i * D_INNER * D_STATE,
        Dp + (size_t)i * D_INNER, zt, yf);
    k_gemm_bb<<<dim3(NROW / 64, 6), dim3(256), 0, stream>>>(
        yf, out_wb + (size_t)i * D_MODEL * D_INNER, nullptr, hidden, nullptr,
        D_INNER, D_INNER, D_MODEL, 0, D_MODEL, 0, 0, 0);
  }
  // ---- head ----
  k_resln<<<dim3(NROW / 4), dim3(256), 0, stream>>>(
      hidden, resid, resid, gamma_f, beta_f, nullptr, hnf, 0, 1);
  k_pool1<<<dim3(BSZ, 14), dim3(128), 0, stream>>>(hnf, partial);
  k_pool2<<<dim3(BSZ), dim3(128), 0, stream>>>(partial, pooled, x2v);
  k_head<<<dim3((NCLS + 255) / 256, BSZ), dim3(256), 0, stream>>>(pooled,
                                                                  protos, x2v,
                                                                  out);
}

// Round 11
// 1986.613 us; speedup vs baseline: 1.1933x; 1.0255x over previous
//
#include <hip/hip_runtime.h>
#include <hip/hip_bf16.h>
#include <math.h>

#define D_MODEL 384
#define D_INNER 768
#define D_STATE 16
#define DT_RANK 24
#define NXP 56          // DT_RANK + 2*D_STATE
#define LTOK 196
#define BSZ 16
#define NROW 3136       // BSZ * LTOK
#define NDEPTH 24
#define NCLS 1000
#define XKC 192         // x_proj split-K chunk (768/4)

constexpr float kSqrtC   = 0.70710678118654752440f;
constexpr float kMaxNorm = 0.95f / 0.70710678118654752440f;   // 1.3435029...

typedef unsigned short u16;
typedef short  bf16x8 __attribute__((ext_vector_type(8)));
typedef u16    u16x8  __attribute__((ext_vector_type(8)));
typedef float  f32x4  __attribute__((ext_vector_type(4)));

__device__ __forceinline__ float clampf(float x, float lo, float hi) {
  return fminf(fmaxf(x, lo), hi);
}

// f32 -> bf16 (RNE)
__device__ __forceinline__ u16 f2bf(float f) {
  union { float f; unsigned u; } v; v.f = f;
  return (u16)((v.u + 0x7FFFu + ((v.u >> 16) & 1u)) >> 16);
}
// bf16 -> f32
__device__ __forceinline__ float bf2f(u16 s) {
  union { unsigned u; float f; } v; v.u = ((unsigned)s) << 16;
  return v.f;
}

// async global->LDS, 16 B per lane. LDS dest = wave-uniform base + lane*16.
__device__ __forceinline__ void gload16(const u16* g, u16* l) {
  __builtin_amdgcn_global_load_lds(
      (const __attribute__((address_space(1))) unsigned int*)g,
      (__attribute__((address_space(3))) unsigned int*)l, 16, 0, 0);
}

// ---- fast transcendentals (1e-7-ish rel err; invisible under bf16) --------
__device__ __forceinline__ float fsig(float x) {
  return __fdividef(1.f, 1.f + __expf(-x));
}
__device__ __forceinline__ float fsilu(float x) { return x * fsig(x); }
__device__ __forceinline__ float fsoftplus(float x) {
  return (x > 20.f) ? x : __logf(1.f + __expf(x));
}
__device__ __forceinline__ float ftanh(float x) {
  float e = __expf(2.f * x);
  return __fdividef(e - 1.f, e + 1.f);
}
__device__ __forceinline__ float fatanh(float x) {   // x in [0, 0.95]
  return 0.5f * __logf(__fdividef(1.f + x, 1.f - x));
}

// 64-lane wave reduction (no LDS, no barriers)
__device__ __forceinline__ float waveSum(float v) {
#pragma unroll
  for (int o = 1; o < 64; o <<= 1) v += __shfl_xor(v, o, 64);
  return v;
}

// block=128 sum-reduce with broadcast (stem kernels only).
__device__ __forceinline__ float blockSum128(float v, float* sm) {
#pragma unroll
  for (int o = 32; o > 0; o >>= 1) v += __shfl_down(v, o, 64);
  __syncthreads();
  if ((threadIdx.x & 63) == 0) sm[threadIdx.x >> 6] = v;
  __syncthreads();
  return sm[0] + sm[1];
}

// ----------------- f32 -> bf16 bulk convert, 5 tensors in one launch --------
__global__ __launch_bounds__(256) void k_cvt5(
    const float* __restrict__ s0, u16* __restrict__ d0, int n0,
    const float* __restrict__ s1, u16* __restrict__ d1, int n1,
    const float* __restrict__ s2, u16* __restrict__ d2, int n2,
    const float* __restrict__ s3, u16* __restrict__ d3, int n3,
    const float* __restrict__ s4, u16* __restrict__ d4, int n4) {
  int i = blockIdx.x * 256 + threadIdx.x;
  const float* s; u16* d;
  if (i < n0) { s = s0; d = d0; }
  else if ((i -= n0) < n1) { s = s1; d = d1; }
  else if ((i -= n1) < n2) { s = s2; d = d2; }
  else if ((i -= n2) < n3) { s = s3; d = d3; }
  else if ((i -= n3) < n4) { s = s4; d = d4; }
  else return;
  float4 v = ((const float4*)s)[i];
  short4 o = {(short)f2bf(v.x), (short)f2bf(v.y), (short)f2bf(v.z),
              (short)f2bf(v.w)};
  *(short4*)&d[(size_t)i * 4] = o;
}

// ------------------------------------------------- im2col (emit bf16) ------
__global__ __launch_bounds__(256) void k_im2col(const float* __restrict__ x,
                                                u16* __restrict__ P) {
  size_t idx = (size_t)blockIdx.x * 256 + threadIdx.x;
  if (idx >= (size_t)NROW * 768) return;
  int k = (int)(idx % 768);
  int r = (int)(idx / 768);
  int b = r / LTOK, t = r % LTOK;
  int hp = t / 14, wp = t % 14;
  int c = k / 256, rem = k % 256, i = rem / 16, j = rem % 16;
  P[idx] = f2bf(
      x[(((size_t)(b * 3 + c) * 224) + hp * 16 + i) * 224 + wp * 16 + j]);
}

// ------------------------- pure-bf16 MFMA GEMM 64x64: C = A*W^T (+b, act) ---
// A (M,K) bf16 rm stride lda. W (Nv,K) bf16 rm tight. REQUIRES K % 64 == 0.
// Double-buffered LDS, ONE barrier per K-step. XOR swizzle on both global
// source and ds_read. Rows >= Nv read garbage; their cols are discarded.
__global__ __launch_bounds__(256) void k_gemm_bb(
    const u16* __restrict__ A, const u16* __restrict__ W,
    const float* __restrict__ bias, void* __restrict__ Cn,
    void* __restrict__ Ct, int K, int lda, int ldc, int ldct, int Nv, int act,
    int obf, int obf_t) {
  __shared__ u16 As[2][64 * 64];
  __shared__ u16 Ws[2][64 * 64];
  const int tid = threadIdx.x;
  const int m0 = blockIdx.x * 64;
  const int n0 = blockIdx.y * 64;
  const int lane = tid & 63;
  const int w = tid >> 6;
  const int wm = w & 1, wn = w >> 1;
  const int lm = lane & 15;
  const int quad = lane >> 4;
  const int r8 = lane >> 3;          // row within chunk, 0..7
  const int t8 = lane & 7;           // 16B slot within row
  const int gsg = t8 ^ r8;           // pre-swizzled global k-segment
  const int s = lm & 7;              // read-time swizzle

  f32x4 acc[2][2];
#pragma unroll
  for (int i = 0; i < 2; i++)
#pragma unroll
    for (int j = 0; j < 2; j++) acc[i][j] = (f32x4){0.f, 0.f, 0.f, 0.f};

  auto stage = [&](int buf, int k0) {
#pragma unroll
    for (int cc = 0; cc < 2; cc++) {
      const int c = 2 * w + cc;            // chunk 0..7 (wave-uniform)
      const int row = c * 8 + r8;
      gload16(A + (size_t)(m0 + row) * lda + k0 + gsg * 8, &As[buf][c * 512]);
      gload16(W + (size_t)(n0 + row) * K + k0 + gsg * 8, &Ws[buf][c * 512]);
    }
  };
  stage(0, 0);
  __syncthreads();
  int cur = 0;
  for (int k0 = 0; k0 < K; k0 += 64) {
    if (k0 + 64 < K) stage(cur ^ 1, k0 + 64);
#pragma unroll
    for (int h = 0; h < 2; h++) {
      const int col = (((h << 2) + quad) ^ s) << 3;
      bf16x8 af[2], bfr[2];
#pragma unroll
      for (int i = 0; i < 2; i++) {
        af[i]  = *(bf16x8*)&As[cur][(wm * 32 + i * 16 + lm) * 64 + col];
        bfr[i] = *(bf16x8*)&Ws[cur][(wn * 32 + i * 16 + lm) * 64 + col];
      }
#pragma unroll
      for (int i = 0; i < 2; i++)
#pragma unroll
        for (int j = 0; j < 2; j++)
          acc[i][j] = __builtin_amdgcn_mfma_f32_16x16x32_bf16(
              af[i], bfr[j], acc[i][j], 0, 0, 0);
    }
    __syncthreads();  // drains prefetch (vmcnt) + guards LDS reuse
    cur ^= 1;
  }
  // epilogue: C/D layout col=lane&15, row=quad*4+reg
#pragma unroll
  for (int i = 0; i < 2; i++) {
#pragma unroll
    for (int j = 0; j < 2; j++) {
      int cg = n0 + wn * 32 + j * 16 + lm;
      if (cg >= Nv) continue;
      float bj = bias ? bias[cg] : 0.f;
      float o[4];
      int rgb = m0 + wm * 32 + i * 16 + quad * 4;
#pragma unroll
      for (int reg = 0; reg < 4; reg++) {
        float v = acc[i][j][reg] + bj;
        if (act == 1) v = fsoftplus(v);
        else if (act == 2 && cg >= 768) v = fsilu(v);
        o[reg] = v;
      }
      if (Cn) {
#pragma unroll
        for (int reg = 0; reg < 4; reg++) {
          if (obf) ((u16*)Cn)[(size_t)(rgb + reg) * ldc + cg] = f2bf(o[reg]);
          else ((float*)Cn)[(size_t)(rgb + reg) * ldc + cg] = o[reg];
        }
      }
      if (Ct) {
        if (obf_t) {
          short4 o4 = {(short)f2bf(o[0]), (short)f2bf(o[1]), (short)f2bf(o[2]),
                       (short)f2bf(o[3])};
          *(short4*)&((u16*)Ct)[(size_t)cg * ldct + rgb] = o4;
        } else {
          float4 o4 = {o[0], o[1], o[2], o[3]};
          *(float4*)&((float*)Ct)[(size_t)cg * ldct + rgb] = o4;
        }
      }
    }
  }
}

// -------- x_proj split-K GEMM: one 64-row block-row, K-chunk per blockIdx.y -
// A (NROW,768) bf16 rm. W (56,768) bf16 rm tight (rows 56..63 read garbage
// from adjacent workspace; discarded). Writes f32 partials
// part[kc][cg][r] (cg<56). K-chunk = XKC = 192 (3 K-steps).
__global__ __launch_bounds__(256) void k_xproj(const u16* __restrict__ A,
                                               const u16* __restrict__ W,
                                               float* __restrict__ part) {
  __shared__ u16 As[2][64 * 64];
  __shared__ u16 Ws[2][64 * 64];
  const int tid = threadIdx.x;
  const int m0 = blockIdx.x * 64;
  const int kb = blockIdx.y * XKC;
  const int lane = tid & 63;
  const int w = tid >> 6;
  const int wm = w & 1, wn = w >> 1;
  const int lm = lane & 15;
  const int quad = lane >> 4;
  const int r8 = lane >> 3;
  const int t8 = lane & 7;
  const int gsg = t8 ^ r8;
  const int s = lm & 7;

  f32x4 acc[2][2];
#pragma unroll
  for (int i = 0; i < 2; i++)
#pragma unroll
    for (int j = 0; j < 2; j++) acc[i][j] = (f32x4){0.f, 0.f, 0.f, 0.f};

  auto stage = [&](int buf, int k0) {
#pragma unroll
    for (int cc = 0; cc < 2; cc++) {
      const int c = 2 * w + cc;
      const int row = c * 8 + r8;
      gload16(A + (size_t)(m0 + row) * 768 + kb + k0 + gsg * 8,
              &As[buf][c * 512]);
      gload16(W + (size_t)row * 768 + kb + k0 + gsg * 8, &Ws[buf][c * 512]);
    }
  };
  stage(0, 0);
  __syncthreads();
  int cur = 0;
  for (int k0 = 0; k0 < XKC; k0 += 64) {
    if (k0 + 64 < XKC) stage(cur ^ 1, k0 + 64);
#pragma unroll
    for (int h = 0; h < 2; h++) {
      const int col = (((h << 2) + quad) ^ s) << 3;
      bf16x8 af[2], bfr[2];
#pragma unroll
      for (int i = 0; i < 2; i++) {
        af[i]  = *(bf16x8*)&As[cur][(wm * 32 + i * 16 + lm) * 64 + col];
        bfr[i] = *(bf16x8*)&Ws[cur][(wn * 32 + i * 16 + lm) * 64 + col];
      }
#pragma unroll
      for (int i = 0; i < 2; i++)
#pragma unroll
        for (int j = 0; j < 2; j++)
          acc[i][j] = __builtin_amdgcn_mfma_f32_16x16x32_bf16(
              af[i], bfr[j], acc[i][j], 0, 0, 0);
    }
    __syncthreads();
    cur ^= 1;
  }
  float* base = part + (size_t)blockIdx.y * NXP * NROW;
#pragma unroll
  for (int i = 0; i < 2; i++) {
#pragma unroll
    for (int j = 0; j < 2; j++) {
      int cg = wn * 32 + j * 16 + lm;
      if (cg >= NXP) continue;
      int rgb = m0 + wm * 32 + i * 16 + quad * 4;
      float4 o4 = {acc[i][j][0], acc[i][j][1], acc[i][j][2], acc[i][j][3]};
      *(float4*)&base[(size_t)cg * NROW + rgb] = o4;
    }
  }
}

// ----- reduce the 4 x_proj K-partials in fixed chunk order (deterministic) --
__global__ __launch_bounds__(256) void k_dred(const float* __restrict__ p,
                                              float* __restrict__ o, int n4) {
  int i = blockIdx.x * 256 + threadIdx.x;
  if (i >= n4) return;
  const float4* pp = (const float4*)p;
  float4 a = pp[i], b = pp[i + n4], c = pp[i + 2 * n4], d = pp[i + 3 * n4];
  float4 r = {((a.x + b.x) + c.x) + d.x, ((a.y + b.y) + c.y) + d.y,
              ((a.z + b.z) + c.z) + d.z, ((a.w + b.w) + c.w) + d.w};
  ((float4*)o)[i] = r;
}

// ----------- in_proj GEMM 64x128: x-half -> Cx rm [r][768], z-half ->
// silu'd TRANSPOSED Zt [768][NROW]. The z-half write goes through an LDS
// transpose (reusing As) so each zt row gets a 64B-contiguous run per
// thread -> no 64B-line write amplification. K%64==0.
__global__ __launch_bounds__(256) void k_gemm_n128(
    const u16* __restrict__ A, const u16* __restrict__ W,
    u16* __restrict__ Cx, u16* __restrict__ Zt, int K, int lda, int ldc) {
  __shared__ u16 As[2][64 * 64];
  __shared__ u16 Ws[2][128 * 64];
  const int tid = threadIdx.x;
  const int m0 = blockIdx.x * 64;
  const int n0 = blockIdx.y * 128;
  const int lane = tid & 63;
  const int w = tid >> 6;
  const int lm = lane & 15;
  const int quad = lane >> 4;
  const int r8 = lane >> 3;
  const int t8 = lane & 7;
  const int gsg = t8 ^ r8;
  const int s = lm & 7;

  f32x4 acc[4][2];
#pragma unroll
  for (int i = 0; i < 4; i++)
#pragma unroll
    for (int j = 0; j < 2; j++) acc[i][j] = (f32x4){0.f, 0.f, 0.f, 0.f};

  auto stage = [&](int buf, int k0) {
#pragma unroll
    for (int cc = 0; cc < 2; cc++) {
      const int c = 2 * w + cc;            // A chunks 0..7
      gload16(A + (size_t)(m0 + c * 8 + r8) * lda + k0 + gsg * 8,
              &As[buf][c * 512]);
    }
#pragma unroll
    for (int cc = 0; cc < 4; cc++) {
      const int c = 4 * w + cc;            // W chunks 0..15
      gload16(W + (size_t)(n0 + c * 8 + r8) * K + k0 + gsg * 8,
              &Ws[buf][c * 512]);
    }
  };
  stage(0, 0);
  __syncthreads();
  int cur = 0;
  for (int k0 = 0; k0 < K; k0 += 64) {
    if (k0 + 64 < K) stage(cur ^ 1, k0 + 64);
#pragma unroll
    for (int h = 0; h < 2; h++) {
      const int col = (((h << 2) + quad) ^ s) << 3;
      bf16x8 af[4], bfr[2];
#pragma unroll
      for (int i = 0; i < 4; i++)
        af[i] = *(bf16x8*)&As[cur][(i * 16 + lm) * 64 + col];
#pragma unroll
      for (int j = 0; j < 2; j++)
        bfr[j] = *(bf16x8*)&Ws[cur][(w * 32 + j * 16 + lm) * 64 + col];
#pragma unroll
      for (int i = 0; i < 4; i++)
#pragma unroll
        for (int j = 0; j < 2; j++)
          acc[i][j] = __builtin_amdgcn_mfma_f32_16x16x32_bf16(
              af[i], bfr[j], acc[i][j], 0, 0, 0);
    }
    __syncthreads();
    cur ^= 1;
  }
  // n0 is 0..767 (x-half) or 768..1535 (z-half) — never mixed (128 | 768).
  if (n0 < 768) {
#pragma unroll
    for (int i = 0; i < 4; i++) {
#pragma unroll
      for (int j = 0; j < 2; j++) {
        int cg = n0 + w * 32 + j * 16 + lm;
        int rgb = m0 + i * 16 + quad * 4;
#pragma unroll
        for (int reg = 0; reg < 4; reg++)
          Cx[(size_t)(rgb + reg) * ldc + cg] = f2bf(acc[i][j][reg]);
      }
    }
  } else {
    // transpose via LDS (reuse As: 128 cols x 64 rows u16 = 16 KB exactly)
    u16* tz = (u16*)As;
#pragma unroll
    for (int i = 0; i < 4; i++) {
#pragma unroll
      for (int j = 0; j < 2; j++) {
        int cl = w * 32 + j * 16 + lm;        // local col 0..127
        int rl = i * 16 + quad * 4;           // local row base
#pragma unroll
        for (int reg = 0; reg < 4; reg++)
          tz[cl * 64 + rl + reg] = f2bf(fsilu(acc[i][j][reg]));
      }
    }
    __syncthreads();
    const int cl = tid >> 1, hf = tid & 1;    // col 0..127, half 0..1
    size_t base = (size_t)(n0 - 768 + cl) * NROW + m0 + hf * 32;
#pragma unroll
    for (int q = 0; q < 4; q++)
      *(u16x8*)&Zt[base + q * 8] = *(u16x8*)&tz[cl * 64 + hf * 32 + q * 8];
  }
}

// ------------------ stem a: expmap0(tokens) -> bf16 h + ||h|| ---------------
__global__ __launch_bounds__(128) void k_stem_a(const float* __restrict__ tok,
                                                u16* __restrict__ hb,
                                                float* __restrict__ xn) {
  __shared__ float sm[2];
  const int r = blockIdx.x, tid = threadIdx.x;
  float v[3];
#pragma unroll
  for (int j = 0; j < 3; j++) v[j] = tok[(size_t)r * D_MODEL + tid + j * 128];
  float s = blockSum128(v[0] * v[0] + v[1] * v[1] + v[2] * v[2], sm);
  float n = sqrtf(s + 1e-15f);
  float nc = clampf(n, 1e-8f, 5.f);
  float ke = tanhf(kSqrtC * nc) / (kSqrtC * nc);
  float rn = sqrtf(ke * ke * s + 1e-15f);
  float sc = rn > kMaxNorm ? kMaxNorm / rn : 1.f;
  float kk = ke * sc;
#pragma unroll
  for (int j = 0; j < 3; j++)
    hb[(size_t)r * D_MODEL + tid + j * 128] = f2bf(kk * v[j]);
  if (tid == 0) xn[r] = fmaxf(sqrtf(kk * kk * s + 1e-15f), 1e-8f);
}

// --- stem b: mobius_matvec tail + mobius_add(hyp_b) + hyp_LN + pos + expmap -
__global__ __launch_bounds__(128) void k_stem_b(
    const float* __restrict__ mx, const float* __restrict__ xn,
    const float* __restrict__ hyp_b, const float* __restrict__ pe_g,
    const float* __restrict__ pe_b, const float* __restrict__ pos,
    float* __restrict__ outh) {
  __shared__ float sm[2];
  const int r = blockIdx.x, tid = threadIdx.x;
  const int t = r % LTOK;
  float mv[3], bv[3];
  int dd[3];
#pragma unroll
  for (int j = 0; j < 3; j++) {
    dd[j] = tid + j * 128;
    mv[j] = mx[(size_t)r * D_MODEL + dd[j]];
    bv[j] = hyp_b[dd[j]];
  }
  float smx = blockSum128(mv[0] * mv[0] + mv[1] * mv[1] + mv[2] * mv[2], sm);
  float mxn = fmaxf(sqrtf(smx + 1e-15f), 1e-8f);
  float xnv = xn[r];
  float tt = tanhf(mxn / xnv * atanhf(fminf(kSqrtC * xnv, 1.f - 1e-5f)));
  float kres = tt / (mxn * kSqrtC);
  float res[3];
#pragma unroll
  for (int j = 0; j < 3; j++) res[j] = kres * mv[j];
  float xy = blockSum128(res[0] * bv[0] + res[1] * bv[1] + res[2] * bv[2], sm);
  float y2 = blockSum128(bv[0] * bv[0] + bv[1] * bv[1] + bv[2] * bv[2], sm);
  float x2 = kres * kres * smx;
  float al = 1.f + xy + 0.5f * y2;
  float be = 1.f - 0.5f * x2;
  float den = fmaxf(1.f + xy + 0.25f * x2 * y2, 1e-15f);
  float h1[3];
#pragma unroll
  for (int j = 0; j < 3; j++) h1[j] = (al * res[j] + be * bv[j]) / den;
  float s1 = blockSum128(h1[0] * h1[0] + h1[1] * h1[1] + h1[2] * h1[2], sm);
  float n1 = sqrtf(s1 + 1e-15f);
  float nc1 = clampf(n1, 1e-8f, kMaxNorm);
  float kl = atanhf(fminf(kSqrtC * nc1, 0.95f)) / (kSqrtC * nc1);
  float tl[3];
#pragma unroll
  for (int j = 0; j < 3; j++) tl[j] = kl * h1[j];
  float mean = blockSum128(tl[0] + tl[1] + tl[2], sm) * (1.f / 384.f);
  float dv = 0.f;
#pragma unroll
  for (int j = 0; j < 3; j++) { float d = tl[j] - mean; dv += d * d; }
  float var = blockSum128(dv, sm) * (1.f / 383.f);
  float inv = 1.f / (sqrtf(var) + 1e-5f);
  float g[3];
#pragma unroll
  for (int j = 0; j < 3; j++)
    g[j] = (tl[j] - mean) * inv * pe_g[dd[j]] + pe_b[dd[j]];
  float sg = blockSum128(g[0] * g[0] + g[1] * g[1] + g[2] * g[2], sm);
  float ng = sqrtf(sg + 1e-15f);
  float nc2 = clampf(ng, 1e-8f, 5.f);
  float ke = tanhf(kSqrtC * nc2) / (kSqrtC * nc2);
  float rn = sqrtf(ke * ke * sg + 1e-15f);
  float sc = rn > kMaxNorm ? kMaxNorm / rn : 1.f;
  float kk = ke * sc;
  float s2 = kk * kk * sg;
  float n3 = sqrtf(s2 + 1e-15f);
  float nc3 = clampf(n3, 1e-8f, kMaxNorm);
  float kl2 = atanhf(fminf(kSqrtC * nc3, 0.95f)) / (kSqrtC * nc3);
  float v[3];
#pragma unroll
  for (int j = 0; j < 3; j++)
    v[j] = kl2 * kk * g[j] + pos[(size_t)t * D_MODEL + dd[j]];
  float sv = blockSum128(v[0] * v[0] + v[1] * v[1] + v[2] * v[2], sm);
  float nv = sqrtf(sv + 1e-15f);
  float nc4 = clampf(nv, 1e-8f, 5.f);
  float ke2 = tanhf(kSqrtC * nc4) / (kSqrtC * nc4);
  float rn2 = sqrtf(ke2 * ke2 * sv + 1e-15f);
  float sc2 = rn2 > kMaxNorm ? kMaxNorm / rn2 : 1.f;
#pragma unroll
  for (int j = 0; j < 3; j++)
    outh[(size_t)r * D_MODEL + dd[j]] = ke2 * sc2 * v[j];
}

// --- residual accumulate + hyp_layernorm, one wave per row (no barriers) ----
__global__ __launch_bounds__(256) void k_resln(
    const float* __restrict__ hid, const float* __restrict__ res_in,
    float* __restrict__ res_out, const float* __restrict__ g_,
    const float* __restrict__ b_, u16* __restrict__ out_bf,
    float* __restrict__ out_f, int first, int out_logmap) {
  const int lane = threadIdx.x & 63;
  const int r = blockIdx.x * 4 + (threadIdx.x >> 6);
  float v[6];
  int dd[6];
#pragma unroll
  for (int j = 0; j < 6; j++) {
    dd[j] = lane + j * 64;
    size_t idx = (size_t)r * D_MODEL + dd[j];
    v[j] = hid[idx] + (first ? 0.f : res_in[idx]);
    res_out[idx] = v[j];
  }
  float ss = 0.f;
#pragma unroll
  for (int j = 0; j < 6; j++) ss += v[j] * v[j];
  float s = waveSum(ss);
  float n = sqrtf(s + 1e-15f);
  float nc = clampf(n, 1e-8f, kMaxNorm);
  float kl = fatanh(fminf(kSqrtC * nc, 0.95f)) / (kSqrtC * nc);
  float t[6];
  float ts = 0.f;
#pragma unroll
  for (int j = 0; j < 6; j++) { t[j] = kl * v[j]; ts += t[j]; }
  float mean = waveSum(ts) * (1.f / 384.f);
  float dv = 0.f;
#pragma unroll
  for (int j = 0; j < 6; j++) { float d = t[j] - mean; dv += d * d; }
  float var = waveSum(dv) * (1.f / 383.f);
  float inv = 1.f / (sqrtf(var) + 1e-5f);
  float g[6];
  float gs = 0.f;
#pragma unroll
  for (int j = 0; j < 6; j++) {
    g[j] = (t[j] - mean) * inv * g_[dd[j]] + b_[dd[j]];
    gs += g[j] * g[j];
  }
  float sg = waveSum(gs);
  float ng = sqrtf(sg + 1e-15f);
  float nc2 = clampf(ng, 1e-8f, 5.f);
  float ke = ftanh(kSqrtC * nc2) / (kSqrtC * nc2);
  float rn = sqrtf(ke * ke * sg + 1e-15f);
  float sc = rn > kMaxNorm ? kMaxNorm / rn : 1.f;
  float kk = ke * sc;
  if (!out_logmap) {
#pragma unroll
    for (int j = 0; j < 6; j++)
      out_bf[(size_t)r * D_MODEL + dd[j]] = f2bf(kk * g[j]);
  } else {
    float s2 = kk * kk * sg;
    float n3 = sqrtf(s2 + 1e-15f);
    float nc3 = clampf(n3, 1e-8f, kMaxNorm);
    float kl2 = fatanh(fminf(kSqrtC * nc3, 0.95f)) / (kSqrtC * nc3);
#pragma unroll
    for (int j = 0; j < 6; j++)
      out_f[(size_t)r * D_MODEL + dd[j]] = kl2 * kk * g[j];
  }
}

// -- conv1d(k=4, causal) + SiLU, tiled; writes u transposed AND normal -------
// Reads the x-half buffer xc [r][768].
__global__ __launch_bounds__(256) void k_convt(const u16* __restrict__ xc,
                                               const float* __restrict__ cw,
                                               const float* __restrict__ cb,
                                               u16* __restrict__ ut,
                                               u16* __restrict__ un) {
  __shared__ u16 sx[52][68];
  __shared__ u16 su2[49][68];
  const int d0 = blockIdx.x * 64;
  const int l0 = blockIdx.y * 49;
  const int b = blockIdx.z;
  const int t = threadIdx.x;
#pragma unroll
  for (int i = 0; i < 4; i++) {
    int idx = t + i * 256;
    if (idx < 832) {
      int row = idx >> 4, seg = idx & 15;
      int l = l0 - 3 + row;
      short4 v = {0, 0, 0, 0};
      if (l >= 0) {
        const u16* p = xc + (size_t)(b * LTOK + l) * D_INNER + d0 + seg * 4;
        v = *(const short4*)p;
      }
      *(short4*)&sx[row][seg * 4] = v;
    }
  }
  __syncthreads();
  const int dl = t & 63, lg = t >> 6;
  const int d = d0 + dl;
  const float c0 = cw[d * 4], c1 = cw[d * 4 + 1], c2 = cw[d * 4 + 2],
              c3 = cw[d * 4 + 3];
  const float bb = cb[d];
  for (int l = lg; l < 49; l += 4) {
    float acc = bb;
    acc = fmaf(c0, bf2f(sx[l + 0][dl]), acc);
    acc = fmaf(c1, bf2f(sx[l + 1][dl]), acc);
    acc = fmaf(c2, bf2f(sx[l + 2][dl]), acc);
    acc = fmaf(c3, bf2f(sx[l + 3][dl]), acc);
    su2[l][dl] = f2bf(fsilu(acc));
  }
  __syncthreads();
#pragma unroll
  for (int i = 0; i < 13; i++) {
    int idx = t + i * 256;
    if (idx < 3136) {
      int d_ = idx / 49, l_ = idx % 49;
      ut[(size_t)(d0 + d_) * NROW + b * LTOK + l0 + l_] = su2[l_][d_];
    }
  }
#pragma unroll
  for (int i = 0; i < 13; i++) {
    int idx = t + i * 256;
    if (idx < 3136) {
      int l_ = idx >> 6, d_ = idx & 63;
      un[(size_t)(b * LTOK + l0 + l_) * D_INNER + d0 + d_] = su2[l_][d_];
    }
  }
}

// ---------- parallel selective scan v11: LDS-op-lean (b64 packed) -----------
__global__ __launch_bounds__(256) void k_pscan(
    const u16* __restrict__ ut, const float* __restrict__ dblt,
    const float* __restrict__ dt_w, const float* __restrict__ dt_bias,
    const float* __restrict__ A_log, const float* __restrict__ Dp,
    const u16* __restrict__ zt, u16* __restrict__ yf) {
  __shared__ float2 sdu[4][196];        // {dt, u}
  __shared__ float sprod[196][18];      // [l][n], pad 18
  const int d0 = blockIdx.x * 4, b = blockIdx.y;
  const int t = threadIdx.x;
  const size_t col0 = (size_t)b * LTOK;
  u16 zz[4] = {0, 0, 0, 0};
  float uo[4];                           // u at l=t, for D*u epilogue
  if (t < 196) {
    float r[DT_RANK];
#pragma unroll
    for (int k = 0; k < DT_RANK; k++)
      r[k] = dblt[(size_t)k * NROW + col0 + t];
#pragma unroll
    for (int g = 0; g < 4; g++) {
      const int d = d0 + g;
      float acc = dt_bias[d];
#pragma unroll
      for (int k = 0; k < DT_RANK; k++)
        acc = fmaf(r[k], dt_w[d * DT_RANK + k], acc);
      float uv = bf2f(ut[(size_t)d * NROW + col0 + t]);
      sdu[g][t] = make_float2(fsoftplus(acc), uv);
      uo[g] = uv;
      zz[g] = zt[(size_t)d * NROW + col0 + t];
    }
  }
  const int c = t & 15, n = t >> 4;
  const bool act = c < 14;
  float Breg[14], Creg[14];
  if (act) {
    const float2* Bp =
        (const float2*)(dblt + (size_t)(DT_RANK + n) * NROW + col0 + c * 14);
    const float2* Cp = (const float2*)(
        dblt + (size_t)(DT_RANK + D_STATE + n) * NROW + col0 + c * 14);
#pragma unroll
    for (int j = 0; j < 7; j++) {
      float2 bv = Bp[j], cv = Cp[j];
      Breg[2 * j] = bv.x; Breg[2 * j + 1] = bv.y;
      Creg[2 * j] = cv.x; Creg[2 * j + 1] = cv.y;
    }
  }
  __syncthreads();   // sdu ready for all waves
  u16 og[4];
#pragma unroll
  for (int g = 0; g < 4; g++) {
    const int d = d0 + g;
    const float a = -__expf(A_log[(size_t)d * D_STATE + n]);
    float dA[14], hh[14];
    float A = 1.f, Bc = 0.f;
    if (act) {
      float2 du[14];
#pragma unroll
      for (int j = 0; j < 14; j++) du[j] = sdu[g][c * 14 + j];
      float h = 0.f, p = 1.f;
#pragma unroll
      for (int j = 0; j < 14; j++) {
        float dtv = du[j].x;
        float e = __expf(dtv * a);
        h = fmaf(e, h, dtv * Breg[j] * du[j].y);
        dA[j] = e;
        hh[j] = h;
        p *= e;
      }
      A = p;
      Bc = h;
    }
#pragma unroll
    for (int off = 1; off < 16; off <<= 1) {
      float pA = __shfl_up(A, off, 16);
      float pB = __shfl_up(Bc, off, 16);
      if (c >= off) {
        Bc = fmaf(A, pB, Bc);
        A *= pA;
      }
    }
    float h0 = __shfl_up(Bc, 1, 16);
    if (c == 0) h0 = 0.f;
    if (g > 0) __syncthreads();   // prev g's reduce reads done before rewrite
    if (act) {
      float p = 1.f;
#pragma unroll
      for (int j = 0; j < 14; j++) {
        p *= dA[j];
        sprod[c * 14 + j][n] = fmaf(p, h0, hh[j]) * Creg[j];
      }
    }
    __syncthreads();   // sprod complete
    if (t < 196) {
      float y = 0.f;
#pragma unroll
      for (int pp = 0; pp < 8; pp++) {
        float2 v = *(float2*)&sprod[t][2 * pp];
        y += v.x;          // n = 2*pp   (order preserved: n = 0..15)
        y += v.y;          // n = 2*pp+1
      }
      float yv = bf2f(f2bf(fmaf(Dp[d], uo[g], y)));
      og[g] = f2bf(yv * bf2f(zz[g]));
    }
  }
  if (t < 196) {
    short4 o4 = {(short)og[0], (short)og[1], (short)og[2], (short)og[3]};
    *(short4*)&yf[(col0 + t) * D_INNER + d0] = o4;
  }
}

// ---------------------- pool phase 1: partial sums over 14-token chunks -----
__global__ __launch_bounds__(128) void k_pool1(const float* __restrict__ tl,
                                               float* __restrict__ partial) {
  const int b = blockIdx.x, g = blockIdx.y, tid = threadIdx.x;
  float m[3] = {0.f, 0.f, 0.f};
  for (int l = g * 14; l < (g + 1) * 14; l++) {
    size_t row = ((size_t)b * LTOK + l) * D_MODEL;
#pragma unroll
    for (int j = 0; j < 3; j++) m[j] += tl[row + tid + j * 128];
  }
#pragma unroll
  for (int j = 0; j < 3; j++)
    partial[((size_t)b * 14 + g) * D_MODEL + tid + j * 128] = m[j];
}

// ------------------ pool phase 2: finalize mean + expmap0 -------------------
__global__ __launch_bounds__(128) void k_pool2(const float* __restrict__ partial,
                                               float* __restrict__ pooled,
                                               float* __restrict__ x2v) {
  __shared__ float sm[2];
  const int b = blockIdx.x, tid = threadIdx.x;
  float m[3] = {0.f, 0.f, 0.f};
  for (int g = 0; g < 14; g++) {
    size_t row = ((size_t)b * 14 + g) * D_MODEL;
#pragma unroll
    for (int j = 0; j < 3; j++) m[j] += partial[row + tid + j * 128];
  }
#pragma unroll
  for (int j = 0; j < 3; j++) m[j] *= (1.f / (float)LTOK);
  float s = blockSum128(m[0] * m[0] + m[1] * m[1] + m[2] * m[2], sm);
  float n = sqrtf(s + 1e-15f);
  float nc = clampf(n, 1e-8f, 5.f);
  float ke = tanhf(kSqrtC * nc) / (kSqrtC * nc);
  float rn = sqrtf(ke * ke * s + 1e-15f);
  float sc = rn > kMaxNorm ? kMaxNorm / rn : 1.f;
  float kk = ke * sc;
  float p[3];
#pragma unroll
  for (int j = 0; j < 3; j++) {
    p[j] = kk * m[j];
    pooled[(size_t)b * D_MODEL + tid + j * 128] = p[j];
  }
  float s2 = blockSum128(p[0] * p[0] + p[1] * p[1] + p[2] * p[2], sm);
  if (tid == 0) x2v[b] = s2;
}

// ------------------- hyperbolic distance head over prototypes ---------------
__global__ __launch_bounds__(256) void k_head(const float* __restrict__ pooled,
                                              const float* __restrict__ protos,
                                              const float* __restrict__ x2v,
                                              float* __restrict__ out) {
  __shared__ float sp[D_MODEL];
  const int b = blockIdx.y;
  const int c = blockIdx.x * 256 + threadIdx.x;
  for (int j = threadIdx.x; j < D_MODEL; j += 256)
    sp[j] = pooled[(size_t)b * D_MODEL + j];
  __syncthreads();
  if (c >= NCLS) return;
  const float* pr = protos + (size_t)c * D_MODEL;
  float dotv = 0.f, y2 = 0.f;
  for (int k = 0; k < D_MODEL; k++) {
    float w = pr[k];
    dotv += sp[k] * w;
    y2 += w * w;
  }
  float x2 = x2v[b];
  float xy = -dotv;
  float al = 1.f + xy + 0.5f * y2;
  float be = 1.f - 0.5f * x2;
  float num2 = al * al * x2 + 2.f * al * be * xy + be * be * y2;
  float den = fmaxf(1.f + xy + 0.25f * x2 * y2, 1e-15f);
  float r2 = num2 / (den * den) + 1e-15f;
  float dn = fminf(kSqrtC * sqrtf(r2), 1.f - 1e-5f);
  out[(size_t)b * NCLS + c] = -(2.f / kSqrtC) * atanhf(dn);
}

// ---------------------------------------------------------------------------
extern "C" void kernel_launch(void* const* d_in, const int* in_sizes, int n_in,
                              void* d_out, int out_size, void* d_ws,
                              size_t ws_size, hipStream_t stream) {
  const float* x        = (const float*)d_in[0];
  const float* patch_w  = (const float*)d_in[1];
  const float* patch_b  = (const float*)d_in[2];
  const float* hyp_w    = (const float*)d_in[3];
  const float* hyp_b    = (const float*)d_in[4];
  const float* pe_gamma = (const float*)d_in[5];
  const float* pe_beta  = (const float*)d_in[6];
  const float* pos      = (const float*)d_in[7];
  const float* in_w     = (const float*)d_in[8];
  const float* conv_w   = (const float*)d_in[9];
  const float* conv_b   = (const float*)d_in[10];
  const float* xp_w     = (const float*)d_in[11];
  const float* dt_w     = (const float*)d_in[12];
  const float* dt_bias  = (const float*)d_in[13];
  const float* A_log    = (const float*)d_in[14];
  const float* Dp       = (const float*)d_in[15];
  const float* out_w    = (const float*)d_in[16];
  const float* gamma    = (const float*)d_in[17];
  const float* beta     = (const float*)d_in[18];
  const float* gamma_f  = (const float*)d_in[19];
  const float* beta_f   = (const float*)d_in[20];
  const float* protos   = (const float*)d_in[21];
  float* out = (float*)d_out;

  // ---- workspace layout ----
  char* cur = (char*)d_ws;
  auto alloc = [&](size_t bytes) {
    char* p = cur;
    cur += (bytes + 255) & ~(size_t)255;
    return (void*)p;
  };
  float* hidden  = (float*)alloc((size_t)NROW * D_MODEL * 4);
  float* resid   = (float*)alloc((size_t)NROW * D_MODEL * 4);
  float* dblt    = (float*)alloc((size_t)64 * NROW * 4);   // dbl^T f32 (56 rows)
  float* dblt4   = (float*)alloc((size_t)4 * NXP * NROW * 4); // split-K partials
  float* fscr    = (float*)alloc((size_t)NROW * 768 * 4);  // stem/head scratch
  float* xn      = (float*)alloc((size_t)NROW * 4);
  float* pooled  = (float*)alloc((size_t)BSZ * D_MODEL * 4);
  float* x2v     = (float*)alloc((size_t)BSZ * 4);
  float* partial = (float*)alloc((size_t)BSZ * 14 * D_MODEL * 4);
  u16* hn_bf  = (u16*)alloc((size_t)NROW * D_MODEL * 2);
  u16* xc_bf  = (u16*)alloc((size_t)NROW * D_INNER * 2);       // in_proj x-half
  u16* zt     = (u16*)alloc((size_t)D_INNER * NROW * 2);       // z^T silu'd
  u16* ut     = (u16*)alloc((size_t)D_INNER * NROW * 2);       // u^T
  u16* u_bf   = (u16*)alloc((size_t)NROW * D_INNER * 2);       // u normal
  u16* yf     = (u16*)alloc((size_t)NROW * D_INNER * 2);       // gated y
  // bf16 weights
  const size_t n_inw  = (size_t)NDEPTH * 2 * D_INNER * D_MODEL;
  const size_t n_outw = (size_t)NDEPTH * D_MODEL * D_INNER;
  const size_t n_xpw  = (size_t)NDEPTH * NXP * D_INNER;
  const size_t n_pw   = (size_t)D_MODEL * 768;
  const size_t n_hw   = (size_t)D_MODEL * D_MODEL;
  u16* in_wb  = (u16*)alloc(n_inw * 2);
  u16* out_wb = (u16*)alloc(n_outw * 2);
  u16* xp_wb  = (u16*)alloc(n_xpw * 2);
  u16* p_wb   = (u16*)alloc(n_pw * 2);
  u16* h_wb   = (u16*)alloc(n_hw * 2);
  // stem/head aliases over dead regions (yf is layer-loop only)
  u16* P_bf     = yf;                               // 3136x768 bf16 im2col
  float* tokens = fscr;                             // 3136x384 f32
  float* mx     = fscr + (size_t)NROW * D_MODEL;    // 3136x384 f32
  float* hnf    = fscr;                             // head: f32 logmap rows

  // ---- weight conversion (single launch) ----
  {
    const int c0 = (int)(n_inw / 4), c1 = (int)(n_outw / 4),
              c2 = (int)(n_xpw / 4), c3 = (int)(n_pw / 4),
              c4 = (int)(n_hw / 4);
    const int tot = c0 + c1 + c2 + c3 + c4;
    k_cvt5<<<dim3((tot + 255) / 256), dim3(256), 0, stream>>>(
        in_w, in_wb, c0, out_w, out_wb, c1, xp_w, xp_wb, c2, patch_w, p_wb,
        c3, hyp_w, h_wb, c4);
  }

  // ---- stem ----
  k_im2col<<<dim3((NROW * 768) / 256), dim3(256), 0, stream>>>(x, P_bf);
  k_gemm_bb<<<dim3(NROW / 64, 6), dim3(256), 0, stream>>>(
      P_bf, p_wb, patch_b, tokens, nullptr, 768, 768, D_MODEL, 0, D_MODEL, 0,
      0, 0);
  k_stem_a<<<dim3(NROW), dim3(128), 0, stream>>>(tokens, hn_bf, xn);
  k_gemm_bb<<<dim3(NROW / 64, 6), dim3(256), 0, stream>>>(
      hn_bf, h_wb, nullptr, mx, nullptr, D_MODEL, D_MODEL, D_MODEL, 0, D_MODEL,
      0, 0, 0);
  k_stem_b<<<dim3(NROW), dim3(128), 0, stream>>>(mx, xn, hyp_b, pe_gamma,
                                                 pe_beta, pos, hidden);
  // ---- layers ----
  const int nred4 = (NXP * NROW) / 4;   // f4 elems per partial
  for (int i = 0; i < NDEPTH; i++) {
    k_resln<<<dim3(NROW / 4), dim3(256), 0, stream>>>(
        hidden, resid, resid, gamma + (size_t)i * D_MODEL,
        beta + (size_t)i * D_MODEL, hn_bf, nullptr, i == 0 ? 1 : 0, 0);
    // in_proj: x-half -> xc_bf rm; z-half silu'd -> zt transposed (LDS path)
    k_gemm_n128<<<dim3(NROW / 64, (2 * D_INNER) / 128), dim3(256), 0, stream>>>(
        hn_bf, in_wb + (size_t)i * 2 * D_INNER * D_MODEL, xc_bf, zt, D_MODEL,
        D_MODEL, D_INNER);
    // conv + silu -> ut (transposed) AND u_bf (normal)
    k_convt<<<dim3(12, 4, BSZ), dim3(256), 0, stream>>>(
        xc_bf, conv_w + (size_t)i * D_INNER * 4, conv_b + (size_t)i * D_INNER,
        ut, u_bf);
    // x_proj split-K=4 -> partials -> deterministic reduce into dblt
    k_xproj<<<dim3(NROW / 64, 4), dim3(256), 0, stream>>>(
        u_bf, xp_wb + (size_t)i * NXP * D_INNER, dblt4);
    k_dred<<<dim3((nred4 + 255) / 256), dim3(256), 0, stream>>>(dblt4, dblt,
                                                                nred4);
    // parallel scan v11 (b64-packed LDS, [l][n] sprod) -> yf [r, 768]
    k_pscan<<<dim3(D_INNER / 4, BSZ), dim3(256), 0, stream>>>(
        ut, dblt, dt_w + (size_t)i * D_INNER * DT_RANK,
        dt_bias + (size_t)i * D_INNER, A_log + (size_t)i * D_INNER * D_STATE,
        Dp + (size_t)i * D_INNER, zt, yf);
    k_gemm_bb<<<dim3(NROW / 64, 6), dim3(256), 0, stream>>>(
        yf, out_wb + (size_t)i * D_MODEL * D_INNER, nullptr, hidden, nullptr,
        D_INNER, D_INNER, D_MODEL, 0, D_MODEL, 0, 0, 0);
  }
  // ---- head ----
  k_resln<<<dim3(NROW / 4), dim3(256), 0, stream>>>(
      hidden, resid, resid, gamma_f, beta_f, nullptr, hnf, 0, 1);
  k_pool1<<<dim3(BSZ, 14), dim3(128), 0, stream>>>(hnf, partial);
  k_pool2<<<dim3(BSZ), dim3(128), 0, stream>>>(partial, pooled, x2v);
  k_head<<<dim3((NCLS + 255) / 256, BSZ), dim3(256), 0, stream>>>(pooled,
                                                                  protos, x2v,
                                                                  out);
}